// Round 7
// baseline (325.631 us; speedup 1.0000x reference)
//
#include <hip/hip_runtime.h>

#define TT 512
#define BB 64
#define DD 768
#define NEG (-1e30f)
#define GW 100   // padded LDS stride per 96-float weight segment

__device__ __forceinline__ float fmax3(float a, float b, float c) {
    return fmaxf(fmaxf(a, b), c);
}
__device__ __forceinline__ int imin3(int a, int b, int c) {
    return min(min(a, b), c);
}
__device__ __forceinline__ float rl(float x, int i) {
    return __int_as_float(__builtin_amdgcn_readlane(__float_as_int(x), i));
}
__device__ __forceinline__ float dot4(float4 a, float4 b) {
    return a.x * b.x + a.y * b.y + a.z * b.z + a.w * b.w;
}

// ---------------------------------------------------------------------------
// Kernel 1: fused skinny GEMM (round-6 version, unchanged).
// ---------------------------------------------------------------------------
__global__ __launch_bounds__(256) void gemm_kernel(
    const float* __restrict__ x,
    const float* __restrict__ W1, const float* __restrict__ b1,
    const float* __restrict__ W2, const float* __restrict__ b2,
    float* __restrict__ o1, float* __restrict__ o2)
{
    __shared__ float wseg[11 * 8 * GW];
    const int tid = threadIdx.x;
    for (int i = tid; i < 11 * DD; i += 256) {
        int m = i / DD, d = i - m * DD;
        int c = d / 96, o = d - c * 96;
        float v = (m < 2) ? W1[d * 2 + m] : W2[d * 9 + (m - 2)];
        wseg[(m * 8 + c) * GW + o] = v;
    }
    __syncthreads();

    const int wave = tid >> 6, lane = tid & 63;
    const int c = lane & 7, g = lane >> 3;
    const int rbase = blockIdx.x * 128 + wave * 32 + g;

    const float4* xp[4];
#pragma unroll
    for (int j = 0; j < 4; ++j)
        xp[j] = reinterpret_cast<const float4*>(x + (size_t)(rbase + 8 * j) * DD);

    float acc[4][11];
#pragma unroll
    for (int j = 0; j < 4; ++j)
#pragma unroll
        for (int m = 0; m < 11; ++m) acc[j][m] = 0.f;

    float4 p0[4], p1[4];
#pragma unroll
    for (int j = 0; j < 4; ++j) { p0[j] = xp[j][c * 24 + 0]; p1[j] = xp[j][c * 24 + 1]; }

    for (int kk = 0; kk < 12; ++kk) {
        const int k0 = 2 * kk, k1 = 2 * kk + 1;
        float4 xa[4];
#pragma unroll
        for (int j = 0; j < 4; ++j) xa[j] = p0[j];
        if (kk < 11) {
#pragma unroll
            for (int j = 0; j < 4; ++j) p0[j] = xp[j][c * 24 + k0 + 2];
        }
#pragma unroll
        for (int m = 0; m < 11; ++m) {
            float4 wv = *reinterpret_cast<const float4*>(&wseg[(m * 8 + c) * GW + 4 * k0]);
#pragma unroll
            for (int j = 0; j < 4; ++j) acc[j][m] += dot4(xa[j], wv);
        }
        float4 xb[4];
#pragma unroll
        for (int j = 0; j < 4; ++j) xb[j] = p1[j];
        if (kk < 11) {
#pragma unroll
            for (int j = 0; j < 4; ++j) p1[j] = xp[j][c * 24 + k1 + 2];
        }
#pragma unroll
        for (int m = 0; m < 11; ++m) {
            float4 wv = *reinterpret_cast<const float4*>(&wseg[(m * 8 + c) * GW + 4 * k1]);
#pragma unroll
            for (int j = 0; j < 4; ++j) acc[j][m] += dot4(xb[j], wv);
        }
    }

#pragma unroll
    for (int j = 0; j < 4; ++j)
#pragma unroll
        for (int m = 0; m < 11; ++m) {
            acc[j][m] += __shfl_xor(acc[j][m], 1);
            acc[j][m] += __shfl_xor(acc[j][m], 2);
            acc[j][m] += __shfl_xor(acc[j][m], 4);
        }

    if (c == 0) {
        float bb1[2] = { b1[0], b1[1] };
        float bb2[9];
#pragma unroll
        for (int m = 0; m < 9; ++m) bb2[m] = b2[m];
#pragma unroll
        for (int j = 0; j < 4; ++j) {
            const int row = rbase + 8 * j;
            o1[row * 2 + 0] = acc[j][0] + bb1[0];
            o1[row * 2 + 1] = acc[j][1] + bb1[1];
#pragma unroll
            for (int m = 0; m < 9; ++m) o2[row * 9 + m] = acc[j][m + 2] + bb2[m];
        }
    }
}

// ---------------------------------------------------------------------------
// Kernel 2: unified CRF kernel, grid = 64 + 64*16 = 1088 blocks x 256 thr.
//  blocks 0..63   : per-seq exact Viterbi + backtrace + tags + counts + scores.
//  blocks 64..1087: (b, chunk) lse chunk transfer matrices (16 x 32 steps).
// Viterbi scans use lgkm-free 32-step register segments (the r7 theory).
// ---------------------------------------------------------------------------
__global__ __launch_bounds__(256) void crf_kernel(
    const float* __restrict__ o1, const float* __restrict__ o2,
    const int* __restrict__ label, const int* __restrict__ seqlen,
    const float* __restrict__ trans1, const float* __restrict__ trans2,
    float* __restrict__ dout,
    float* __restrict__ M1, float* __restrict__ M2,
    float* __restrict__ scores, float* __restrict__ counts)
{
    __shared__ float s_l2[TT][9];
    __shared__ float s_l1[TT][2];
    __shared__ int   s_lab[TT];
    __shared__ float s_tr2[81];
    __shared__ float s_tr1[4];
    __shared__ unsigned char s_bp2[9][TT];    // column-major: [state][t]
    __shared__ unsigned char s_bp1[2][TT];
    __shared__ unsigned char s_path2[16][9][36];
    __shared__ unsigned char s_path1[16][2][36];
    __shared__ unsigned char s_sel2[16], s_sel1[16];
    __shared__ float s_part[2][4];
    __shared__ int s_last2, s_last1;
    __shared__ int s_cnt[4][3];

    const int tid  = threadIdx.x;
    const int wave = tid >> 6, lane = tid & 63;

    if (blockIdx.x >= 64) {
        // ================= lse chunk-matrix block (32 steps) =================
        const int bc  = blockIdx.x - 64;
        const int b   = bc >> 4, cch = bc & 15;
        const int sl  = seqlen[b];
        const int t0  = cch * 32 + 1;
        const int cap = (cch < 15) ? 32 : 31;
        int n = sl - t0; n = n < 0 ? 0 : (n > cap ? cap : n);

        for (int i = tid; i < cap * 9; i += 256) {
            int t = i / 9, k = i - t * 9;
            s_l2[t][k] = o2[((size_t)b * TT + t0 + t) * 9 + k];
        }
        for (int i = tid; i < cap * 2; i += 256) {
            int t = i >> 1, k = i & 1;
            s_l1[t][k] = o1[((size_t)b * TT + t0 + t) * 2 + k];
        }
        if (tid < 81) s_tr2[tid] = trans2[tid];
        if (tid >= 128 && tid < 132) s_tr1[tid - 128] = trans1[tid - 128];
        __syncthreads();

        if (wave < 2) {
            int L, i_row, jj, base2; bool active;
            if (wave == 0) {
                if (lane < 63) { active = true;  L = 9; i_row = lane / 9; jj = lane - i_row * 9; base2 = i_row * 9; }
                else           { active = false; L = 9; i_row = 0; jj = 0; base2 = 54; }
            } else {
                if (lane < 18)      { active = true;  L = 9; i_row = 7 + lane / 9; jj = lane % 9; base2 = (lane / 9) * 9; }
                else if (lane < 22) { active = true;  L = 2; i_row = (lane - 18) >> 1; jj = (lane - 18) & 1; base2 = 18 + ((lane - 18) & ~1); }
                else                { active = false; L = 2; i_row = 0; jj = 0; base2 = 18; }
            }

            float tcol[9], row[9];
#pragma unroll
            for (int k = 0; k < 9; ++k) {
                tcol[k] = (k < L) ? ((L == 9) ? s_tr2[k * 9 + jj] : s_tr1[k * 2 + jj]) : NEG;
                row[k]  = (k < L && k == i_row) ? 0.f : NEG;
            }
            const float* lp = (L == 9) ? &s_l2[0][jj] : &s_l1[0][jj];
            const int lstride = L;

            for (int tt = 0; tt < n; ++tt) {
                float l = lp[tt * lstride];
                float v[9];
#pragma unroll
                for (int k = 0; k < 9; ++k) v[k] = row[k] + tcol[k];
                float m = fmax3(fmax3(v[0], v[1], v[2]), fmax3(v[3], v[4], v[5]), fmax3(v[6], v[7], v[8]));
                float s = 0.f;
#pragma unroll
                for (int k = 0; k < 9; ++k) s += __expf(v[k] - m);
                float nv = m + __logf(s) + l;
#pragma unroll
                for (int k = 0; k < 9; ++k) {
                    float sv = __shfl(nv, base2 + (k < L ? k : 0));
                    row[k] = (k < L) ? sv : NEG;
                }
            }
            if (active) {
                if (L == 9) M2[((size_t)(b * 16 + cch)) * 81 + i_row * 9 + jj] = row[jj];
                else        M1[((size_t)(b * 16 + cch)) * 4  + i_row * 2 + jj] = row[jj];
            }
        }
        return;
    }

    // ================= per-sequence Viterbi block =================
    const int b  = blockIdx.x;
    const int sl = seqlen[b];

    // phase 0: vectorized staging + identity bp prefill (column-major)
    {
        const float4* src = (const float4*)(o2 + (size_t)b * TT * 9);
        float4* dst = (float4*)&s_l2[0][0];
        for (int i = tid; i < TT * 9 / 4; i += 256) dst[i] = src[i];
    }
    {
        const float4* src = (const float4*)(o1 + (size_t)b * TT * 2);
        float4* dst = (float4*)&s_l1[0][0];
        for (int i = tid; i < TT * 2 / 4; i += 256) dst[i] = src[i];
    }
    {
        const int4* src = (const int4*)(label + (size_t)b * TT);
        int4* dst = (int4*)s_lab;
        for (int i = tid; i < TT / 4; i += 256) dst[i] = src[i];
    }
    if (tid < 81) s_tr2[tid] = trans2[tid];
    if (tid >= 96 && tid < 100) s_tr1[tid - 96] = trans1[tid - 96];
    for (int i = tid; i < 9 * TT; i += 256) ((unsigned char*)s_bp2)[i] = (unsigned char)(i >> 9);
    for (int i = tid; i < 2 * TT; i += 256) ((unsigned char*)s_bp1)[i] = (unsigned char)(i >> 9);
    __syncthreads();

    // phase 1: forward scans + score sums
    if (wave == 0) {
        // ---- CRF2 Viterbi forward: lgkm-free register segments ----
        if (lane < 9) {
            const int j = lane;
            float tc0 = s_tr2[0 * 9 + j], tc1 = s_tr2[1 * 9 + j], tc2 = s_tr2[2 * 9 + j];
            float tc3 = s_tr2[3 * 9 + j], tc4 = s_tr2[4 * 9 + j], tc5 = s_tr2[5 * 9 + j];
            float tc6 = s_tr2[6 * 9 + j], tc7 = s_tr2[7 * 9 + j], tc8 = s_tr2[8 * 9 + j];
            float av = s_l2[0][j];
            float a0 = rl(av, 0), a1 = rl(av, 1), a2 = rl(av, 2);
            float a3 = rl(av, 3), a4 = rl(av, 4), a5 = rl(av, 5);
            float a6 = rl(av, 6), a7 = rl(av, 7), a8 = rl(av, 8);

            for (int seg = 0; seg < 16 && seg * 32 < sl; ++seg) {
                const int t0 = seg * 32;
                float lg[32];
#pragma unroll
                for (int u = 0; u < 32; ++u) lg[u] = s_l2[t0 + u][j];
                unsigned int bpk[8];
#pragma unroll
                for (int q = 0; q < 8; ++q) bpk[q] = 0u;
#pragma unroll
                for (int u = 0; u < 32; ++u) {
                    const int t = t0 + u;
                    if (t >= 1 && t < sl) {
                        float v0 = a0 + tc0, v1 = a1 + tc1, v2 = a2 + tc2;
                        float v3 = a3 + tc3, v4 = a4 + tc4, v5 = a5 + tc5;
                        float v6 = a6 + tc6, v7 = a7 + tc7, v8 = a8 + tc8;
                        float m = fmax3(fmax3(v0, v1, v2), fmax3(v3, v4, v5), fmax3(v6, v7, v8));
                        int c0 = (v0 == m) ? 0 : 15, c1 = (v1 == m) ? 1 : 15, c2 = (v2 == m) ? 2 : 15;
                        int c3 = (v3 == m) ? 3 : 15, c4 = (v4 == m) ? 4 : 15, c5 = (v5 == m) ? 5 : 15;
                        int c6 = (v6 == m) ? 6 : 15, c7 = (v7 == m) ? 7 : 15, c8 = (v8 == m) ? 8 : 15;
                        int bi = imin3(imin3(c0, c1, c2), imin3(c3, c4, c5), imin3(c6, c7, c8));
                        bpk[u >> 2] |= (unsigned int)bi << ((u & 3) * 8);
                        float nj = m + lg[u];
                        a0 = rl(nj, 0); a1 = rl(nj, 1); a2 = rl(nj, 2);
                        a3 = rl(nj, 3); a4 = rl(nj, 4); a5 = rl(nj, 5);
                        a6 = rl(nj, 6); a7 = rl(nj, 7); a8 = rl(nj, 8);
                    }
                }
#pragma unroll
                for (int q = 0; q < 8; ++q) {
                    const int tq = t0 + 4 * q;
                    if (tq + 3 < sl) {
                        *(unsigned int*)&s_bp2[j][tq] = bpk[q];
                    } else {
#pragma unroll
                        for (int bb = 0; bb < 4; ++bb) {
                            const int t = tq + bb;
                            if (t >= 1 && t < sl)
                                s_bp2[j][t] = (unsigned char)((bpk[q] >> (bb * 8)) & 0xffu);
                        }
                    }
                }
            }
            if (lane == 0) {
                float m = fmax3(fmax3(a0, a1, a2), fmax3(a3, a4, a5), fmax3(a6, a7, a8));
                int c0 = (a0 == m) ? 0 : 15, c1 = (a1 == m) ? 1 : 15, c2 = (a2 == m) ? 2 : 15;
                int c3 = (a3 == m) ? 3 : 15, c4 = (a4 == m) ? 4 : 15, c5 = (a5 == m) ? 5 : 15;
                int c6 = (a6 == m) ? 6 : 15, c7 = (a7 == m) ? 7 : 15, c8 = (a8 == m) ? 8 : 15;
                s_last2 = imin3(imin3(c0, c1, c2), imin3(c3, c4, c5), imin3(c6, c7, c8));
            }
        }
    } else if (wave == 1) {
        // ---- CRF1 Viterbi forward: lanes 0,1, lgkm-free segments ----
        if (lane < 2) {
            const int j = lane;
            float tc0 = s_tr1[0 * 2 + j], tc1 = s_tr1[1 * 2 + j];
            float av = s_l1[0][j];
            float a0 = rl(av, 0), a1 = rl(av, 1);
            for (int seg = 0; seg < 16 && seg * 32 < sl; ++seg) {
                const int t0 = seg * 32;
                float lg[32];
#pragma unroll
                for (int u = 0; u < 32; ++u) lg[u] = s_l1[t0 + u][j];
                unsigned int bpk[8];
#pragma unroll
                for (int q = 0; q < 8; ++q) bpk[q] = 0u;
#pragma unroll
                for (int u = 0; u < 32; ++u) {
                    const int t = t0 + u;
                    if (t >= 1 && t < sl) {
                        float v0 = a0 + tc0, v1 = a1 + tc1;
                        int bp = (v1 > v0) ? 1 : 0;
                        bpk[u >> 2] |= (unsigned int)bp << ((u & 3) * 8);
                        float nj = fmaxf(v0, v1) + lg[u];
                        a0 = rl(nj, 0); a1 = rl(nj, 1);
                    }
                }
#pragma unroll
                for (int q = 0; q < 8; ++q) {
                    const int tq = t0 + 4 * q;
                    if (tq + 3 < sl) {
                        *(unsigned int*)&s_bp1[j][tq] = bpk[q];
                    } else {
#pragma unroll
                        for (int bb = 0; bb < 4; ++bb) {
                            const int t = tq + bb;
                            if (t >= 1 && t < sl)
                                s_bp1[j][t] = (unsigned char)((bpk[q] >> (bb * 8)) & 0xffu);
                        }
                    }
                }
            }
            if (lane == 0) s_last1 = (a1 > a0) ? 1 : 0;
        }
    } else {
        const int t0i = tid - 128;
        float u1 = 0.f, bs1 = 0.f, u2 = 0.f, bs2 = 0.f;
        for (int t = t0i; t < sl; t += 128) {
            int lb = s_lab[t]; int lb1 = lb > 0 ? 1 : 0;
            u1 += s_l1[t][lb1];
            u2 += s_l2[t][lb];
            if (t >= 1) {
                int lp = s_lab[t - 1]; int lp1 = lp > 0 ? 1 : 0;
                bs1 += s_tr1[lp1 * 2 + lb1];
                bs2 += s_tr2[lp * 9 + lb];
            }
        }
        for (int off = 32; off; off >>= 1) {
            u1 += __shfl_down(u1, off); bs1 += __shfl_down(bs1, off);
            u2 += __shfl_down(u2, off); bs2 += __shfl_down(bs2, off);
        }
        if (lane == 0) {
            s_part[wave - 2][0] = u1; s_part[wave - 2][1] = bs1;
            s_part[wave - 2][2] = u2; s_part[wave - 2][3] = bs2;
        }
    }
    __syncthreads();

    // phase 2: chunk-parallel backtraces (16 chunks x 32 steps, exact)
    if (tid < 144) {
        int cch = tid / 9, e = tid - cch * 9;
        int pe = (cch < 15) ? (cch + 1) * 32 : 511;
        int tag = e;
        for (int t = pe; t > cch * 32; --t) {
            tag = s_bp2[tag][t];
            s_path2[cch][e][t - 1 - cch * 32] = (unsigned char)tag;
        }
    } else if (tid >= 160 && tid < 192) {
        int k = tid - 160, cch = k >> 1, e = k & 1;
        int pe = (cch < 15) ? (cch + 1) * 32 : 511;
        int tag = e;
        for (int t = pe; t > cch * 32; --t) {
            tag = s_bp1[tag][t];
            s_path1[cch][e][t - 1 - cch * 32] = (unsigned char)tag;
        }
    } else if (tid >= 224 && tid < 228) {
        int k = tid - 224;
        scores[b * 4 + k] = s_part[0][k] + s_part[1][k];
    }
    __syncthreads();

    // phase 3: boundary resolve
    if (tid == 0) {
        int cur = s_last2;
        for (int c = 15; c >= 0; --c) { s_sel2[c] = (unsigned char)cur; cur = s_path2[c][cur][0]; }
    } else if (tid == 1) {
        int cur = s_last1;
        for (int c = 15; c >= 0; --c) { s_sel1[c] = (unsigned char)cur; cur = s_path1[c][cur][0]; }
    }
    __syncthreads();

    // phase 4: assemble tags + accuracy counts
    {
        int c1 = 0, c2 = 0, cc = 0;
        for (int p = tid; p < TT; p += 256) {
            int ch = p >> 5;
            int v2 = (p == 511) ? s_last2 : (int)s_path2[ch][s_sel2[ch]][p & 31];
            int v1 = (p == 511) ? s_last1 : (int)s_path1[ch][s_sel1[ch]][p & 31];
            int comb = (v1 == 0) ? 0 : v2;
            dout[(size_t)b * TT + p] = (float)comb;
            if (p < sl) {
                int lb = s_lab[p]; int lb1 = lb > 0 ? 1 : 0;
                c1 += (v1 == lb1); c2 += (v2 == lb); cc += (comb == lb);
            }
        }
        for (int off = 32; off; off >>= 1) {
            c1 += __shfl_down(c1, off); c2 += __shfl_down(c2, off); cc += __shfl_down(cc, off);
        }
        if (lane == 0) { s_cnt[wave][0] = c1; s_cnt[wave][1] = c2; s_cnt[wave][2] = cc; }
    }
    __syncthreads();
    if (tid == 0) {
        counts[b * 3 + 0] = (float)(s_cnt[0][0] + s_cnt[1][0] + s_cnt[2][0] + s_cnt[3][0]);
        counts[b * 3 + 1] = (float)(s_cnt[0][1] + s_cnt[1][1] + s_cnt[2][1] + s_cnt[3][1]);
        counts[b * 3 + 2] = (float)(s_cnt[0][2] + s_cnt[1][2] + s_cnt[2][2] + s_cnt[3][2]);
    }
}

// ---------------------------------------------------------------------------
// Kernel 3: fold 16 chunk matrices -> log-norm -> ll per seq (one wave per
// 4 sequences, readlane broadcasts, lgkm-free), then reduce all scalars.
// 1 block x 1024 threads = 16 waves.
// ---------------------------------------------------------------------------
__global__ __launch_bounds__(1024) void finalize_kernel(
    const float* __restrict__ o1, const float* __restrict__ o2,
    const float* __restrict__ M1, const float* __restrict__ M2,
    const float* __restrict__ scores, const float* __restrict__ counts,
    const int* __restrict__ seqlen, float* __restrict__ out)
{
    __shared__ float s_ll1[64], s_ll2[64];
    const int tid = threadIdx.x;
    const int wave = tid >> 6, lane = tid & 63;

    for (int si = 0; si < 4; ++si) {
        const int s = wave * 4 + si;
        if (lane < 9) {
            const int r = lane;
            float av = o2[(size_t)s * TT * 9 + r];
            float a0 = rl(av, 0), a1 = rl(av, 1), a2 = rl(av, 2);
            float a3 = rl(av, 3), a4 = rl(av, 4), a5 = rl(av, 5);
            float a6 = rl(av, 6), a7 = rl(av, 7), a8 = rl(av, 8);
            for (int c = 0; c < 16; ++c) {
                const float* M = &M2[((size_t)(s * 16 + c)) * 81];
                float v0 = a0 + M[0 * 9 + r], v1 = a1 + M[1 * 9 + r], v2 = a2 + M[2 * 9 + r];
                float v3 = a3 + M[3 * 9 + r], v4 = a4 + M[4 * 9 + r], v5 = a5 + M[5 * 9 + r];
                float v6 = a6 + M[6 * 9 + r], v7 = a7 + M[7 * 9 + r], v8 = a8 + M[8 * 9 + r];
                float m = fmax3(fmax3(v0, v1, v2), fmax3(v3, v4, v5), fmax3(v6, v7, v8));
                float su = __expf(v0 - m) + __expf(v1 - m) + __expf(v2 - m)
                         + __expf(v3 - m) + __expf(v4 - m) + __expf(v5 - m)
                         + __expf(v6 - m) + __expf(v7 - m) + __expf(v8 - m);
                float na = m + __logf(su);
                a0 = rl(na, 0); a1 = rl(na, 1); a2 = rl(na, 2);
                a3 = rl(na, 3); a4 = rl(na, 4); a5 = rl(na, 5);
                a6 = rl(na, 6); a7 = rl(na, 7); a8 = rl(na, 8);
            }
            if (lane == 0) {
                float m = fmax3(fmax3(a0, a1, a2), fmax3(a3, a4, a5), fmax3(a6, a7, a8));
                float su = __expf(a0 - m) + __expf(a1 - m) + __expf(a2 - m)
                         + __expf(a3 - m) + __expf(a4 - m) + __expf(a5 - m)
                         + __expf(a6 - m) + __expf(a7 - m) + __expf(a8 - m);
                float ln = m + __logf(su);
                s_ll2[s] = (scores[s * 4 + 2] + scores[s * 4 + 3]) - ln;
            }
        } else if (lane >= 16 && lane < 18) {
            const int jj = lane - 16;
            float av = o1[(size_t)s * TT * 2 + jj];
            float a0 = rl(av, 16), a1 = rl(av, 17);
            for (int c = 0; c < 16; ++c) {
                const float* M = &M1[((size_t)(s * 16 + c)) * 4];
                float v0 = a0 + M[0 * 2 + jj], v1 = a1 + M[1 * 2 + jj];
                float mm = fmaxf(v0, v1);
                float na = mm + __logf(__expf(v0 - mm) + __expf(v1 - mm));
                a0 = rl(na, 16); a1 = rl(na, 17);
            }
            if (jj == 0) {
                float mm = fmaxf(a0, a1);
                float ln = mm + __logf(__expf(a0 - mm) + __expf(a1 - mm));
                s_ll1[s] = (scores[s * 4 + 0] + scores[s * 4 + 1]) - ln;
            }
        }
    }
    __syncthreads();

    if (tid < 64) {
        float v1 = s_ll1[tid], v2 = s_ll2[tid];
        float a1 = counts[tid * 3 + 0], a2 = counts[tid * 3 + 1], ac = counts[tid * 3 + 2];
        float slf = (float)seqlen[tid];
        for (int off = 32; off; off >>= 1) {
            v1 += __shfl_down(v1, off); v2 += __shfl_down(v2, off);
            a1 += __shfl_down(a1, off); a2 += __shfl_down(a2, off);
            ac += __shfl_down(ac, off); slf += __shfl_down(slf, off);
        }
        if (tid == 0) {
            float loss1 = -v1 / 64.f;
            float loss2 = -v2 / 64.f;
            out[BB * TT + 0] = (loss1 + 8.f * loss2) / 9.f;
            out[BB * TT + 1] = a1 / slf;
            out[BB * TT + 2] = a2 / slf;
            out[BB * TT + 3] = ac / slf;
        }
    }
}

extern "C" void kernel_launch(void* const* d_in, const int* in_sizes, int n_in,
                              void* d_out, int out_size, void* d_ws, size_t ws_size,
                              hipStream_t stream) {
    (void)in_sizes; (void)n_in; (void)out_size; (void)ws_size;
    const float* x      = (const float*)d_in[0];
    const int*   label  = (const int*)d_in[1];
    const int*   seqlen = (const int*)d_in[2];
    const float* W1     = (const float*)d_in[3];
    const float* b1     = (const float*)d_in[4];
    const float* W2     = (const float*)d_in[5];
    const float* b2     = (const float*)d_in[6];
    const float* trans1 = (const float*)d_in[7];
    const float* trans2 = (const float*)d_in[8];
    float* out = (float*)d_out;
    float* ws  = (float*)d_ws;

    float* o1     = ws;                      // 65536
    float* o2     = o1 + BB * TT * 2;        // 294912
    float* M2     = o2 + BB * TT * 9;        // 64*16*81 = 82944
    float* M1     = M2 + 64 * 16 * 81;       // 4096
    float* scores = M1 + 64 * 16 * 4;        // 256
    float* counts = scores + 64 * 4;         // 192

    gemm_kernel<<<256, 256, 0, stream>>>(x, W1, b1, W2, b2, o1, o2);
    crf_kernel<<<1088, 256, 0, stream>>>(o1, o2, label, seqlen, trans1, trans2,
                                         out, M1, M2, scores, counts);
    finalize_kernel<<<1, 1024, 0, stream>>>(o1, o2, M1, M2, scores, counts, seqlen, out);
}

// Round 8
// 239.397 us; speedup vs baseline: 1.3602x; 1.3602x over previous
//
#include <hip/hip_runtime.h>

#define TT 512
#define BB 64
#define DD 768
#define NEG (-1e30f)

__device__ __forceinline__ float fmax3(float a, float b, float c) {
    return fmaxf(fmaxf(a, b), c);
}
__device__ __forceinline__ int imin3(int a, int b, int c) {
    return min(min(a, b), c);
}
__device__ __forceinline__ float rl(float x, int i) {
    return __int_as_float(__builtin_amdgcn_readlane(__float_as_int(x), i));
}
__device__ __forceinline__ float dot4(float4 a, float4 b) {
    return a.x * b.x + a.y * b.y + a.z * b.z + a.w * b.w;
}
__device__ __forceinline__ void gl_lds16(const float* g, float* l) {
    __builtin_amdgcn_global_load_lds(
        (const __attribute__((address_space(1))) void*)g,
        (__attribute__((address_space(3))) void*)l, 16, 0, 0);
}

// ---------------------------------------------------------------------------
// Kernel 1: fused skinny GEMM, LDS-staged via global_load_lds (width 16).
// Grid 256 x 256. Block owns 128 rows. K tiled 12 x 64 floats, double-buffered
// x_tile[2][128][64] (2x32KB). Staging: thread t, chunk i -> element
// e = i*256 + t; LDS offset e*16B == uniform + lane*16 (HW requirement);
// global addr coalesced (consecutive t -> consecutive 16B).
// Compute: lane (g=lane>>3, c=lane&7): 4 rows {g,g+8,g+16,g+24}+wave*32,
// 8-float k-segment c. Reduce over c-lanes via shfl_xor.
// ---------------------------------------------------------------------------
__global__ __launch_bounds__(256) void gemm_kernel(
    const float* __restrict__ x,
    const float* __restrict__ W1, const float* __restrict__ b1,
    const float* __restrict__ W2, const float* __restrict__ b2,
    float* __restrict__ o1, float* __restrict__ o2)
{
    __shared__ float wT[11][DD];
    __shared__ float x_tile[2][128 * 64];

    const int tid = threadIdx.x;
    const int wave = tid >> 6, lane = tid & 63;

    // stage weights transposed (one-time, ~33KB)
    for (int i = tid; i < 11 * DD; i += 256) {
        int m = i / DD, d = i - m * DD;
        wT[m][d] = (m < 2) ? W1[d * 2 + m] : W2[d * 9 + (m - 2)];
    }

    const int row0 = blockIdx.x * 128;
    // async stage of tile kt into buffer bf
#define STAGE_TILE(KT, BF) { \
        _Pragma("unroll") \
        for (int i = 0; i < 8; ++i) { \
            const int e = i * 256 + tid; \
            const int r = e >> 4, q = e & 15; \
            const float* gp = x + ((size_t)(row0 + r) * DD + (KT) * 64 + q * 4); \
            gl_lds16(gp, &x_tile[BF][e * 4]); \
        } }

    STAGE_TILE(0, 0);
    __syncthreads();   // drains wT ds_writes (lgkm) + tile0 (vmcnt)

    const int c = lane & 7, g = lane >> 3;
    const int rw = wave * 32 + g;

    float acc[4][11];
#pragma unroll
    for (int j = 0; j < 4; ++j)
#pragma unroll
        for (int m = 0; m < 11; ++m) acc[j][m] = 0.f;

    for (int kt = 0; kt < 12; ++kt) {
        const int cur = kt & 1;
        if (kt + 1 < 12) STAGE_TILE(kt + 1, cur ^ 1);

        float4 xr[4][2];
#pragma unroll
        for (int j = 0; j < 4; ++j) {
            const float* xp = &x_tile[cur][(rw + 8 * j) * 64 + c * 8];
            xr[j][0] = *(const float4*)(xp);
            xr[j][1] = *(const float4*)(xp + 4);
        }
#pragma unroll
        for (int m = 0; m < 11; ++m) {
            const float* wp = &wT[m][kt * 64 + c * 8];
            float4 wa = *(const float4*)(wp);
            float4 wb = *(const float4*)(wp + 4);
#pragma unroll
            for (int j = 0; j < 4; ++j)
                acc[j][m] += dot4(xr[j][0], wa) + dot4(xr[j][1], wb);
        }
        __syncthreads();   // drains next tile's loads; syncs buffer reuse
    }

    // reduce over the 8 c-lanes
#pragma unroll
    for (int j = 0; j < 4; ++j)
#pragma unroll
        for (int m = 0; m < 11; ++m) {
            acc[j][m] += __shfl_xor(acc[j][m], 1);
            acc[j][m] += __shfl_xor(acc[j][m], 2);
            acc[j][m] += __shfl_xor(acc[j][m], 4);
        }

    if (c == 0) {
        float bb1[2] = { b1[0], b1[1] };
        float bb2[9];
#pragma unroll
        for (int m = 0; m < 9; ++m) bb2[m] = b2[m];
#pragma unroll
        for (int j = 0; j < 4; ++j) {
            const int row = row0 + rw + 8 * j;
            o1[row * 2 + 0] = acc[j][0] + bb1[0];
            o1[row * 2 + 1] = acc[j][1] + bb1[1];
#pragma unroll
            for (int m = 0; m < 9; ++m) o2[row * 9 + m] = acc[j][m + 2] + bb2[m];
        }
    }
#undef STAGE_TILE
}

// ---------------------------------------------------------------------------
// Kernel 2: unified CRF kernel, grid = 64 + 1024 blocks x 256 threads.
//  blocks 0..63   : per-seq exact Viterbi + backtrace + tags + counts + scores.
//  blocks 64..1087: (b, chunk) lse chunk transfer matrices (16 x 32 steps).
// Viterbi scans: spill-proof 8-step register segments; one ds_write_b64 of
// packed backpointers per 8 steps.
// ---------------------------------------------------------------------------
__global__ __launch_bounds__(256) void crf_kernel(
    const float* __restrict__ o1, const float* __restrict__ o2,
    const int* __restrict__ label, const int* __restrict__ seqlen,
    const float* __restrict__ trans1, const float* __restrict__ trans2,
    float* __restrict__ dout,
    float* __restrict__ M1, float* __restrict__ M2,
    float* __restrict__ scores, float* __restrict__ counts)
{
    __shared__ float s_l2[TT][9];
    __shared__ float s_l1[TT][2];
    __shared__ int   s_lab[TT];
    __shared__ float s_tr2[81];
    __shared__ float s_tr1[4];
    __shared__ __align__(8) unsigned char s_bp2[9][TT];
    __shared__ __align__(8) unsigned char s_bp1[2][TT];
    __shared__ unsigned char s_path2[16][9][36];
    __shared__ unsigned char s_path1[16][2][36];
    __shared__ unsigned char s_sel2[16], s_sel1[16];
    __shared__ float s_part[2][4];
    __shared__ int s_last2, s_last1;
    __shared__ int s_cnt[4][3];

    const int tid  = threadIdx.x;
    const int wave = tid >> 6, lane = tid & 63;

    if (blockIdx.x >= 64) {
        // ================= lse chunk-matrix block (32 steps) =================
        const int bc  = blockIdx.x - 64;
        const int b   = bc >> 4, cch = bc & 15;
        const int sl  = seqlen[b];
        const int t0  = cch * 32 + 1;
        const int cap = (cch < 15) ? 32 : 31;
        int n = sl - t0; n = n < 0 ? 0 : (n > cap ? cap : n);

        for (int i = tid; i < cap * 9; i += 256) {
            int t = i / 9, k = i - t * 9;
            s_l2[t][k] = o2[((size_t)b * TT + t0 + t) * 9 + k];
        }
        for (int i = tid; i < cap * 2; i += 256) {
            int t = i >> 1, k = i & 1;
            s_l1[t][k] = o1[((size_t)b * TT + t0 + t) * 2 + k];
        }
        if (tid < 81) s_tr2[tid] = trans2[tid];
        if (tid >= 128 && tid < 132) s_tr1[tid - 128] = trans1[tid - 128];
        __syncthreads();

        if (wave < 2) {
            int L, i_row, jj, base2; bool active;
            if (wave == 0) {
                if (lane < 63) { active = true;  L = 9; i_row = lane / 9; jj = lane - i_row * 9; base2 = i_row * 9; }
                else           { active = false; L = 9; i_row = 0; jj = 0; base2 = 54; }
            } else {
                if (lane < 18)      { active = true;  L = 9; i_row = 7 + lane / 9; jj = lane % 9; base2 = (lane / 9) * 9; }
                else if (lane < 22) { active = true;  L = 2; i_row = (lane - 18) >> 1; jj = (lane - 18) & 1; base2 = 18 + ((lane - 18) & ~1); }
                else                { active = false; L = 2; i_row = 0; jj = 0; base2 = 18; }
            }

            float tcol[9], row[9];
#pragma unroll
            for (int k = 0; k < 9; ++k) {
                tcol[k] = (k < L) ? ((L == 9) ? s_tr2[k * 9 + jj] : s_tr1[k * 2 + jj]) : NEG;
                row[k]  = (k < L && k == i_row) ? 0.f : NEG;
            }
            const float* lp = (L == 9) ? &s_l2[0][jj] : &s_l1[0][jj];
            const int lstride = L;

            for (int tt = 0; tt < n; ++tt) {
                float l = lp[tt * lstride];
                float v[9];
#pragma unroll
                for (int k = 0; k < 9; ++k) v[k] = row[k] + tcol[k];
                float m = fmax3(fmax3(v[0], v[1], v[2]), fmax3(v[3], v[4], v[5]), fmax3(v[6], v[7], v[8]));
                float s = 0.f;
#pragma unroll
                for (int k = 0; k < 9; ++k) s += __expf(v[k] - m);
                float nv = m + __logf(s) + l;
#pragma unroll
                for (int k = 0; k < 9; ++k) {
                    float sv = __shfl(nv, base2 + (k < L ? k : 0));
                    row[k] = (k < L) ? sv : NEG;
                }
            }
            if (active) {
                if (L == 9) M2[((size_t)(b * 16 + cch)) * 81 + i_row * 9 + jj] = row[jj];
                else        M1[((size_t)(b * 16 + cch)) * 4  + i_row * 2 + jj] = row[jj];
            }
        }
        return;
    }

    // ================= per-sequence Viterbi block =================
    const int b  = blockIdx.x;
    const int sl = seqlen[b];

    // phase 0: vectorized staging + identity bp prefill (column-major)
    {
        const float4* src = (const float4*)(o2 + (size_t)b * TT * 9);
        float4* dst = (float4*)&s_l2[0][0];
        for (int i = tid; i < TT * 9 / 4; i += 256) dst[i] = src[i];
    }
    {
        const float4* src = (const float4*)(o1 + (size_t)b * TT * 2);
        float4* dst = (float4*)&s_l1[0][0];
        for (int i = tid; i < TT * 2 / 4; i += 256) dst[i] = src[i];
    }
    {
        const int4* src = (const int4*)(label + (size_t)b * TT);
        int4* dst = (int4*)s_lab;
        for (int i = tid; i < TT / 4; i += 256) dst[i] = src[i];
    }
    if (tid < 81) s_tr2[tid] = trans2[tid];
    if (tid >= 96 && tid < 100) s_tr1[tid - 96] = trans1[tid - 96];
    for (int i = tid; i < 9 * TT; i += 256) ((unsigned char*)s_bp2)[i] = (unsigned char)(i >> 9);
    for (int i = tid; i < 2 * TT; i += 256) ((unsigned char*)s_bp1)[i] = (unsigned char)(i >> 9);
    __syncthreads();

    // phase 1: forward scans + score sums
    if (wave == 0) {
        // ---- CRF2 Viterbi forward (lanes 0..8), 8-step register segments ----
        if (lane < 9) {
            const int j = lane;
            float tc0 = s_tr2[0 * 9 + j], tc1 = s_tr2[1 * 9 + j], tc2 = s_tr2[2 * 9 + j];
            float tc3 = s_tr2[3 * 9 + j], tc4 = s_tr2[4 * 9 + j], tc5 = s_tr2[5 * 9 + j];
            float tc6 = s_tr2[6 * 9 + j], tc7 = s_tr2[7 * 9 + j], tc8 = s_tr2[8 * 9 + j];
            float av = s_l2[0][j];
            float a0 = rl(av, 0), a1 = rl(av, 1), a2 = rl(av, 2);
            float a3 = rl(av, 3), a4 = rl(av, 4), a5 = rl(av, 5);
            float a6 = rl(av, 6), a7 = rl(av, 7), a8 = rl(av, 8);

#define VSTEP2(LG, BI) { \
            float v0=a0+tc0, v1=a1+tc1, v2=a2+tc2, v3=a3+tc3, v4=a4+tc4; \
            float v5=a5+tc5, v6=a6+tc6, v7=a7+tc7, v8=a8+tc8; \
            float mm = fmax3(fmax3(v0,v1,v2), fmax3(v3,v4,v5), fmax3(v6,v7,v8)); \
            int c0=(v0==mm)?0:15, c1=(v1==mm)?1:15, c2=(v2==mm)?2:15; \
            int c3=(v3==mm)?3:15, c4=(v4==mm)?4:15, c5=(v5==mm)?5:15; \
            int c6=(v6==mm)?6:15, c7=(v7==mm)?7:15, c8=(v8==mm)?8:15; \
            BI = imin3(imin3(c0,c1,c2), imin3(c3,c4,c5), imin3(c6,c7,c8)); \
            float nj = mm + (LG); \
            a0=rl(nj,0); a1=rl(nj,1); a2=rl(nj,2); a3=rl(nj,3); a4=rl(nj,4); \
            a5=rl(nj,5); a6=rl(nj,6); a7=rl(nj,7); a8=rl(nj,8); }

            // prologue: t = 1..7
            for (int t = 1; t < 8 && t < sl; ++t) {
                float lg = s_l2[t][j];
                int bi; VSTEP2(lg, bi);
                s_bp2[j][t] = (unsigned char)bi;
            }
            // main: unconditional 8-step segments
            int t0 = 8;
            for (; t0 + 8 <= sl; t0 += 8) {
                float l0 = s_l2[t0 + 0][j], l1 = s_l2[t0 + 1][j];
                float l2 = s_l2[t0 + 2][j], l3 = s_l2[t0 + 3][j];
                float l4 = s_l2[t0 + 4][j], l5 = s_l2[t0 + 5][j];
                float l6 = s_l2[t0 + 6][j], l7 = s_l2[t0 + 7][j];
                int bi; unsigned int lo, hi;
                VSTEP2(l0, bi); lo  = (unsigned int)bi;
                VSTEP2(l1, bi); lo |= (unsigned int)bi << 8;
                VSTEP2(l2, bi); lo |= (unsigned int)bi << 16;
                VSTEP2(l3, bi); lo |= (unsigned int)bi << 24;
                VSTEP2(l4, bi); hi  = (unsigned int)bi;
                VSTEP2(l5, bi); hi |= (unsigned int)bi << 8;
                VSTEP2(l6, bi); hi |= (unsigned int)bi << 16;
                VSTEP2(l7, bi); hi |= (unsigned int)bi << 24;
                *(unsigned long long*)&s_bp2[j][t0] =
                    (unsigned long long)lo | ((unsigned long long)hi << 32);
            }
            // tail
            for (int t = t0; t < sl; ++t) {
                float lg = s_l2[t][j];
                int bi; VSTEP2(lg, bi);
                s_bp2[j][t] = (unsigned char)bi;
            }
#undef VSTEP2
            if (lane == 0) {
                float mm = fmax3(fmax3(a0, a1, a2), fmax3(a3, a4, a5), fmax3(a6, a7, a8));
                int c0 = (a0 == mm) ? 0 : 15, c1 = (a1 == mm) ? 1 : 15, c2 = (a2 == mm) ? 2 : 15;
                int c3 = (a3 == mm) ? 3 : 15, c4 = (a4 == mm) ? 4 : 15, c5 = (a5 == mm) ? 5 : 15;
                int c6 = (a6 == mm) ? 6 : 15, c7 = (a7 == mm) ? 7 : 15, c8 = (a8 == mm) ? 8 : 15;
                s_last2 = imin3(imin3(c0, c1, c2), imin3(c3, c4, c5), imin3(c6, c7, c8));
            }
        }
    } else if (wave == 1) {
        // ---- CRF1 Viterbi forward (lanes 0..1), 8-step register segments ----
        if (lane < 2) {
            const int j = lane;
            float tc0 = s_tr1[0 * 2 + j], tc1 = s_tr1[1 * 2 + j];
            float av = s_l1[0][j];
            float a0 = rl(av, 0), a1 = rl(av, 1);

#define VSTEP1(LG, BI) { \
            float v0 = a0 + tc0, v1 = a1 + tc1; \
            BI = (v1 > v0) ? 1 : 0; \
            float nj = fmaxf(v0, v1) + (LG); \
            a0 = rl(nj, 0); a1 = rl(nj, 1); }

            for (int t = 1; t < 8 && t < sl; ++t) {
                float lg = s_l1[t][j];
                int bi; VSTEP1(lg, bi);
                s_bp1[j][t] = (unsigned char)bi;
            }
            int t0 = 8;
            for (; t0 + 8 <= sl; t0 += 8) {
                float l0 = s_l1[t0 + 0][j], l1 = s_l1[t0 + 1][j];
                float l2 = s_l1[t0 + 2][j], l3 = s_l1[t0 + 3][j];
                float l4 = s_l1[t0 + 4][j], l5 = s_l1[t0 + 5][j];
                float l6 = s_l1[t0 + 6][j], l7 = s_l1[t0 + 7][j];
                int bi; unsigned int lo, hi;
                VSTEP1(l0, bi); lo  = (unsigned int)bi;
                VSTEP1(l1, bi); lo |= (unsigned int)bi << 8;
                VSTEP1(l2, bi); lo |= (unsigned int)bi << 16;
                VSTEP1(l3, bi); lo |= (unsigned int)bi << 24;
                VSTEP1(l4, bi); hi  = (unsigned int)bi;
                VSTEP1(l5, bi); hi |= (unsigned int)bi << 8;
                VSTEP1(l6, bi); hi |= (unsigned int)bi << 16;
                VSTEP1(l7, bi); hi |= (unsigned int)bi << 24;
                *(unsigned long long*)&s_bp1[j][t0] =
                    (unsigned long long)lo | ((unsigned long long)hi << 32);
            }
            for (int t = t0; t < sl; ++t) {
                float lg = s_l1[t][j];
                int bi; VSTEP1(lg, bi);
                s_bp1[j][t] = (unsigned char)bi;
            }
#undef VSTEP1
            if (lane == 0) s_last1 = (a1 > a0) ? 1 : 0;
        }
    } else {
        const int t0i = tid - 128;
        float u1 = 0.f, bs1 = 0.f, u2 = 0.f, bs2 = 0.f;
        for (int t = t0i; t < sl; t += 128) {
            int lb = s_lab[t]; int lb1 = lb > 0 ? 1 : 0;
            u1 += s_l1[t][lb1];
            u2 += s_l2[t][lb];
            if (t >= 1) {
                int lp = s_lab[t - 1]; int lp1 = lp > 0 ? 1 : 0;
                bs1 += s_tr1[lp1 * 2 + lb1];
                bs2 += s_tr2[lp * 9 + lb];
            }
        }
        for (int off = 32; off; off >>= 1) {
            u1 += __shfl_down(u1, off); bs1 += __shfl_down(bs1, off);
            u2 += __shfl_down(u2, off); bs2 += __shfl_down(bs2, off);
        }
        if (lane == 0) {
            s_part[wave - 2][0] = u1; s_part[wave - 2][1] = bs1;
            s_part[wave - 2][2] = u2; s_part[wave - 2][3] = bs2;
        }
    }
    __syncthreads();

    // phase 2: chunk-parallel backtraces (16 chunks x 32 steps, exact)
    if (tid < 144) {
        int cch = tid / 9, e = tid - cch * 9;
        int pe = (cch < 15) ? (cch + 1) * 32 : 511;
        int tag = e;
        for (int t = pe; t > cch * 32; --t) {
            tag = s_bp2[tag][t];
            s_path2[cch][e][t - 1 - cch * 32] = (unsigned char)tag;
        }
    } else if (tid >= 160 && tid < 192) {
        int k = tid - 160, cch = k >> 1, e = k & 1;
        int pe = (cch < 15) ? (cch + 1) * 32 : 511;
        int tag = e;
        for (int t = pe; t > cch * 32; --t) {
            tag = s_bp1[tag][t];
            s_path1[cch][e][t - 1 - cch * 32] = (unsigned char)tag;
        }
    } else if (tid >= 224 && tid < 228) {
        int k = tid - 224;
        scores[b * 4 + k] = s_part[0][k] + s_part[1][k];
    }
    __syncthreads();

    // phase 3: boundary resolve
    if (tid == 0) {
        int cur = s_last2;
        for (int c = 15; c >= 0; --c) { s_sel2[c] = (unsigned char)cur; cur = s_path2[c][cur][0]; }
    } else if (tid == 1) {
        int cur = s_last1;
        for (int c = 15; c >= 0; --c) { s_sel1[c] = (unsigned char)cur; cur = s_path1[c][cur][0]; }
    }
    __syncthreads();

    // phase 4: assemble tags + accuracy counts
    {
        int c1 = 0, c2 = 0, cc = 0;
        for (int p = tid; p < TT; p += 256) {
            int ch = p >> 5;
            int v2 = (p == 511) ? s_last2 : (int)s_path2[ch][s_sel2[ch]][p & 31];
            int v1 = (p == 511) ? s_last1 : (int)s_path1[ch][s_sel1[ch]][p & 31];
            int comb = (v1 == 0) ? 0 : v2;
            dout[(size_t)b * TT + p] = (float)comb;
            if (p < sl) {
                int lb = s_lab[p]; int lb1 = lb > 0 ? 1 : 0;
                c1 += (v1 == lb1); c2 += (v2 == lb); cc += (comb == lb);
            }
        }
        for (int off = 32; off; off >>= 1) {
            c1 += __shfl_down(c1, off); c2 += __shfl_down(c2, off); cc += __shfl_down(cc, off);
        }
        if (lane == 0) { s_cnt[wave][0] = c1; s_cnt[wave][1] = c2; s_cnt[wave][2] = cc; }
    }
    __syncthreads();
    if (tid == 0) {
        counts[b * 3 + 0] = (float)(s_cnt[0][0] + s_cnt[1][0] + s_cnt[2][0] + s_cnt[3][0]);
        counts[b * 3 + 1] = (float)(s_cnt[0][1] + s_cnt[1][1] + s_cnt[2][1] + s_cnt[3][1]);
        counts[b * 3 + 2] = (float)(s_cnt[0][2] + s_cnt[1][2] + s_cnt[2][2] + s_cnt[3][2]);
    }
}

// ---------------------------------------------------------------------------
// Kernel 3: per-seq fold of 16 chunk matrices (M staged in LDS; VALU-only
// chain) -> log-norm -> ll per seq. Grid 64 x 64 (one wave per seq).
// ---------------------------------------------------------------------------
__global__ __launch_bounds__(64) void finalize_kernel(
    const float* __restrict__ o1, const float* __restrict__ o2,
    const float* __restrict__ M1, const float* __restrict__ M2,
    const float* __restrict__ scores,
    float* __restrict__ ll1, float* __restrict__ ll2)
{
    __shared__ float sM2[16 * 81];
    __shared__ float sM1[16 * 4];
    const int s = blockIdx.x, lane = threadIdx.x;

    for (int i = lane; i < 16 * 81; i += 64) sM2[i] = M2[(size_t)s * 16 * 81 + i];
    for (int i = lane; i < 16 * 4;  i += 64) sM1[i] = M1[(size_t)s * 16 * 4 + i];
    __syncthreads();

    if (lane < 9) {
        const int r = lane;
        float av = o2[(size_t)s * TT * 9 + r];
        float a0 = rl(av, 0), a1 = rl(av, 1), a2 = rl(av, 2);
        float a3 = rl(av, 3), a4 = rl(av, 4), a5 = rl(av, 5);
        float a6 = rl(av, 6), a7 = rl(av, 7), a8 = rl(av, 8);
        for (int c = 0; c < 16; ++c) {
            const float* M = &sM2[c * 81];
            float v0 = a0 + M[0 * 9 + r], v1 = a1 + M[1 * 9 + r], v2 = a2 + M[2 * 9 + r];
            float v3 = a3 + M[3 * 9 + r], v4 = a4 + M[4 * 9 + r], v5 = a5 + M[5 * 9 + r];
            float v6 = a6 + M[6 * 9 + r], v7 = a7 + M[7 * 9 + r], v8 = a8 + M[8 * 9 + r];
            float m = fmax3(fmax3(v0, v1, v2), fmax3(v3, v4, v5), fmax3(v6, v7, v8));
            float su = __expf(v0 - m) + __expf(v1 - m) + __expf(v2 - m)
                     + __expf(v3 - m) + __expf(v4 - m) + __expf(v5 - m)
                     + __expf(v6 - m) + __expf(v7 - m) + __expf(v8 - m);
            float na = m + __logf(su);
            a0 = rl(na, 0); a1 = rl(na, 1); a2 = rl(na, 2);
            a3 = rl(na, 3); a4 = rl(na, 4); a5 = rl(na, 5);
            a6 = rl(na, 6); a7 = rl(na, 7); a8 = rl(na, 8);
        }
        if (lane == 0) {
            float m = fmax3(fmax3(a0, a1, a2), fmax3(a3, a4, a5), fmax3(a6, a7, a8));
            float su = __expf(a0 - m) + __expf(a1 - m) + __expf(a2 - m)
                     + __expf(a3 - m) + __expf(a4 - m) + __expf(a5 - m)
                     + __expf(a6 - m) + __expf(a7 - m) + __expf(a8 - m);
            float ln = m + __logf(su);
            ll2[s] = (scores[s * 4 + 2] + scores[s * 4 + 3]) - ln;
        }
    } else if (lane >= 16 && lane < 18) {
        const int jj = lane - 16;
        float av = o1[(size_t)s * TT * 2 + jj];
        float a0 = rl(av, 16), a1 = rl(av, 17);
        for (int c = 0; c < 16; ++c) {
            const float* M = &sM1[c * 4];
            float v0 = a0 + M[0 * 2 + jj], v1 = a1 + M[1 * 2 + jj];
            float mm = fmaxf(v0, v1);
            float na = mm + __logf(__expf(v0 - mm) + __expf(v1 - mm));
            a0 = rl(na, 16); a1 = rl(na, 17);
        }
        if (jj == 0) {
            float mm = fmaxf(a0, a1);
            float ln = mm + __logf(__expf(a0 - mm) + __expf(a1 - mm));
            ll1[s] = (scores[s * 4 + 0] + scores[s * 4 + 1]) - ln;
        }
    }
}

// ---------------------------------------------------------------------------
// Kernel 4: final scalar reduction (1 block, 64 threads)
// ---------------------------------------------------------------------------
__global__ __launch_bounds__(64) void reduce_kernel(
    const float* __restrict__ ll1, const float* __restrict__ ll2,
    const float* __restrict__ counts, const int* __restrict__ seqlen,
    float* __restrict__ out)
{
    const int t = threadIdx.x;
    float v1 = ll1[t], v2 = ll2[t];
    float a1 = counts[t * 3 + 0], a2 = counts[t * 3 + 1], ac = counts[t * 3 + 2];
    float slf = (float)seqlen[t];
    for (int off = 32; off; off >>= 1) {
        v1 += __shfl_down(v1, off); v2 += __shfl_down(v2, off);
        a1 += __shfl_down(a1, off); a2 += __shfl_down(a2, off);
        ac += __shfl_down(ac, off); slf += __shfl_down(slf, off);
    }
    if (t == 0) {
        float loss1 = -v1 / 64.f;
        float loss2 = -v2 / 64.f;
        out[BB * TT + 0] = (loss1 + 8.f * loss2) / 9.f;
        out[BB * TT + 1] = a1 / slf;
        out[BB * TT + 2] = a2 / slf;
        out[BB * TT + 3] = ac / slf;
    }
}

extern "C" void kernel_launch(void* const* d_in, const int* in_sizes, int n_in,
                              void* d_out, int out_size, void* d_ws, size_t ws_size,
                              hipStream_t stream) {
    (void)in_sizes; (void)n_in; (void)out_size; (void)ws_size;
    const float* x      = (const float*)d_in[0];
    const int*   label  = (const int*)d_in[1];
    const int*   seqlen = (const int*)d_in[2];
    const float* W1     = (const float*)d_in[3];
    const float* b1     = (const float*)d_in[4];
    const float* W2     = (const float*)d_in[5];
    const float* b2     = (const float*)d_in[6];
    const float* trans1 = (const float*)d_in[7];
    const float* trans2 = (const float*)d_in[8];
    float* out = (float*)d_out;
    float* ws  = (float*)d_ws;

    float* o1     = ws;                      // 65536
    float* o2     = o1 + BB * TT * 2;        // 294912
    float* M2     = o2 + BB * TT * 9;        // 64*16*81 = 82944
    float* M1     = M2 + 64 * 16 * 81;       // 4096
    float* scores = M1 + 64 * 16 * 4;        // 256
    float* counts = scores + 64 * 4;         // 192
    float* ll1    = counts + 64 * 3;         // 64
    float* ll2    = ll1 + BB;                // 64

    gemm_kernel<<<256, 256, 0, stream>>>(x, W1, b1, W2, b2, o1, o2);
    crf_kernel<<<1088, 256, 0, stream>>>(o1, o2, label, seqlen, trans1, trans2,
                                         out, M1, M2, scores, counts);
    finalize_kernel<<<64, 64, 0, stream>>>(o1, o2, M1, M2, scores, ll1, ll2);
    reduce_kernel<<<1, 64, 0, stream>>>(ll1, ll2, counts, seqlen, out);
}

// Round 9
// 222.309 us; speedup vs baseline: 1.4648x; 1.0769x over previous
//
#include <hip/hip_runtime.h>

#define TT 512
#define BB 64
#define DD 768
#define NEG (-1e30f)

__device__ __forceinline__ float fmax3(float a, float b, float c) {
    return fmaxf(fmaxf(a, b), c);
}
__device__ __forceinline__ int imin3(int a, int b, int c) {
    return min(min(a, b), c);
}
__device__ __forceinline__ float rl(float x, int i) {
    return __int_as_float(__builtin_amdgcn_readlane(__float_as_int(x), i));
}
__device__ __forceinline__ float dot4(float4 a, float4 b) {
    return a.x * b.x + a.y * b.y + a.z * b.z + a.w * b.w;
}
__device__ __forceinline__ void gl_lds16(const float* g, float* l) {
    __builtin_amdgcn_global_load_lds(
        (const __attribute__((address_space(1))) void*)g,
        (__attribute__((address_space(3))) void*)l, 16, 0, 0);
}

// ---------------------------------------------------------------------------
// Kernel 1: fused skinny GEMM, LDS-staged via global_load_lds (r8, unchanged).
// ---------------------------------------------------------------------------
__global__ __launch_bounds__(256) void gemm_kernel(
    const float* __restrict__ x,
    const float* __restrict__ W1, const float* __restrict__ b1,
    const float* __restrict__ W2, const float* __restrict__ b2,
    float* __restrict__ o1, float* __restrict__ o2)
{
    __shared__ float wT[11][DD];
    __shared__ float x_tile[2][128 * 64];

    const int tid = threadIdx.x;
    const int wave = tid >> 6, lane = tid & 63;

    for (int i = tid; i < 11 * DD; i += 256) {
        int m = i / DD, d = i - m * DD;
        wT[m][d] = (m < 2) ? W1[d * 2 + m] : W2[d * 9 + (m - 2)];
    }

    const int row0 = blockIdx.x * 128;
#define STAGE_TILE(KT, BF) { \
        _Pragma("unroll") \
        for (int i = 0; i < 8; ++i) { \
            const int e = i * 256 + tid; \
            const int r = e >> 4, q = e & 15; \
            const float* gp = x + ((size_t)(row0 + r) * DD + (KT) * 64 + q * 4); \
            gl_lds16(gp, &x_tile[BF][e * 4]); \
        } }

    STAGE_TILE(0, 0);
    __syncthreads();

    const int c = lane & 7, g = lane >> 3;
    const int rw = wave * 32 + g;

    float acc[4][11];
#pragma unroll
    for (int j = 0; j < 4; ++j)
#pragma unroll
        for (int m = 0; m < 11; ++m) acc[j][m] = 0.f;

    for (int kt = 0; kt < 12; ++kt) {
        const int cur = kt & 1;
        if (kt + 1 < 12) STAGE_TILE(kt + 1, cur ^ 1);

        float4 xr[4][2];
#pragma unroll
        for (int j = 0; j < 4; ++j) {
            const float* xp = &x_tile[cur][(rw + 8 * j) * 64 + c * 8];
            xr[j][0] = *(const float4*)(xp);
            xr[j][1] = *(const float4*)(xp + 4);
        }
#pragma unroll
        for (int m = 0; m < 11; ++m) {
            const float* wp = &wT[m][kt * 64 + c * 8];
            float4 wa = *(const float4*)(wp);
            float4 wb = *(const float4*)(wp + 4);
#pragma unroll
            for (int j = 0; j < 4; ++j)
                acc[j][m] += dot4(xr[j][0], wa) + dot4(xr[j][1], wb);
        }
        __syncthreads();
    }

#pragma unroll
    for (int j = 0; j < 4; ++j)
#pragma unroll
        for (int m = 0; m < 11; ++m) {
            acc[j][m] += __shfl_xor(acc[j][m], 1);
            acc[j][m] += __shfl_xor(acc[j][m], 2);
            acc[j][m] += __shfl_xor(acc[j][m], 4);
        }

    if (c == 0) {
        float bb1[2] = { b1[0], b1[1] };
        float bb2[9];
#pragma unroll
        for (int m = 0; m < 9; ++m) bb2[m] = b2[m];
#pragma unroll
        for (int j = 0; j < 4; ++j) {
            const int row = row0 + rw + 8 * j;
            o1[row * 2 + 0] = acc[j][0] + bb1[0];
            o1[row * 2 + 1] = acc[j][1] + bb1[1];
#pragma unroll
            for (int m = 0; m < 9; ++m) o2[row * 9 + m] = acc[j][m + 2] + bb2[m];
        }
    }
#undef STAGE_TILE
}

// ---------------------------------------------------------------------------
// Kernel 2: unified CRF kernel, grid = 64 + 1024 blocks x 256 threads.
//  blocks 0..63   : per-seq exact Viterbi. Forward scan stores ONLY alphas
//                   (lean ~16-instr step); backpointers reconstructed in a
//                   parallel phase from stored alphas (bit-exact: fp max is
//                   exact, identical expressions -> identical bits).
//  blocks 64..1087: (b, chunk) lse chunk transfer matrices (16 x 32 steps).
// ---------------------------------------------------------------------------
__global__ __launch_bounds__(256) void crf_kernel(
    const float* __restrict__ o1, const float* __restrict__ o2,
    const int* __restrict__ label, const int* __restrict__ seqlen,
    const float* __restrict__ trans1, const float* __restrict__ trans2,
    float* __restrict__ dout,
    float* __restrict__ M1, float* __restrict__ M2,
    float* __restrict__ scores, float* __restrict__ counts)
{
    __shared__ float s_l2[TT][9];
    __shared__ float s_l1[TT][2];
    __shared__ float s_alpha2[TT][9];
    __shared__ float s_alpha1[TT][2];
    __shared__ int   s_lab[TT];
    __shared__ float s_tr2[81];
    __shared__ float s_tr1[4];
    __shared__ unsigned char s_bp2[9][TT];
    __shared__ unsigned char s_bp1[2][TT];
    __shared__ unsigned char s_path2[16][9][36];
    __shared__ unsigned char s_path1[16][2][36];
    __shared__ unsigned char s_sel2[16], s_sel1[16];
    __shared__ float s_part[2][4];
    __shared__ int s_last2, s_last1;
    __shared__ int s_cnt[4][3];

    const int tid  = threadIdx.x;
    const int wave = tid >> 6, lane = tid & 63;

    if (blockIdx.x >= 64) {
        // ================= lse chunk-matrix block (32 steps) =================
        const int bc  = blockIdx.x - 64;
        const int b   = bc >> 4, cch = bc & 15;
        const int sl  = seqlen[b];
        const int t0  = cch * 32 + 1;
        const int cap = (cch < 15) ? 32 : 31;
        int n = sl - t0; n = n < 0 ? 0 : (n > cap ? cap : n);

        for (int i = tid; i < cap * 9; i += 256) {
            int t = i / 9, k = i - t * 9;
            s_l2[t][k] = o2[((size_t)b * TT + t0 + t) * 9 + k];
        }
        for (int i = tid; i < cap * 2; i += 256) {
            int t = i >> 1, k = i & 1;
            s_l1[t][k] = o1[((size_t)b * TT + t0 + t) * 2 + k];
        }
        if (tid < 81) s_tr2[tid] = trans2[tid];
        if (tid >= 128 && tid < 132) s_tr1[tid - 128] = trans1[tid - 128];
        __syncthreads();

        if (wave < 2) {
            int L, i_row, jj, base2; bool active;
            if (wave == 0) {
                if (lane < 63) { active = true;  L = 9; i_row = lane / 9; jj = lane - i_row * 9; base2 = i_row * 9; }
                else           { active = false; L = 9; i_row = 0; jj = 0; base2 = 54; }
            } else {
                if (lane < 18)      { active = true;  L = 9; i_row = 7 + lane / 9; jj = lane % 9; base2 = (lane / 9) * 9; }
                else if (lane < 22) { active = true;  L = 2; i_row = (lane - 18) >> 1; jj = (lane - 18) & 1; base2 = 18 + ((lane - 18) & ~1); }
                else                { active = false; L = 2; i_row = 0; jj = 0; base2 = 18; }
            }

            float tcol[9], row[9];
#pragma unroll
            for (int k = 0; k < 9; ++k) {
                tcol[k] = (k < L) ? ((L == 9) ? s_tr2[k * 9 + jj] : s_tr1[k * 2 + jj]) : NEG;
                row[k]  = (k < L && k == i_row) ? 0.f : NEG;
            }
            const float* lp = (L == 9) ? &s_l2[0][jj] : &s_l1[0][jj];
            const int lstride = L;

            for (int tt = 0; tt < n; ++tt) {
                float l = lp[tt * lstride];
                float v[9];
#pragma unroll
                for (int k = 0; k < 9; ++k) v[k] = row[k] + tcol[k];
                float m = fmax3(fmax3(v[0], v[1], v[2]), fmax3(v[3], v[4], v[5]), fmax3(v[6], v[7], v[8]));
                float s = 0.f;
#pragma unroll
                for (int k = 0; k < 9; ++k) s += __expf(v[k] - m);
                float nv = m + __logf(s) + l;
#pragma unroll
                for (int k = 0; k < 9; ++k) {
                    float sv = __shfl(nv, base2 + (k < L ? k : 0));
                    row[k] = (k < L) ? sv : NEG;
                }
            }
            if (active) {
                if (L == 9) M2[((size_t)(b * 16 + cch)) * 81 + i_row * 9 + jj] = row[jj];
                else        M1[((size_t)(b * 16 + cch)) * 4  + i_row * 2 + jj] = row[jj];
            }
        }
        return;
    }

    // ================= per-sequence Viterbi block =================
    const int b  = blockIdx.x;
    const int sl = seqlen[b];

    // phase 0: vectorized staging + identity bp prefill
    {
        const float4* src = (const float4*)(o2 + (size_t)b * TT * 9);
        float4* dst = (float4*)&s_l2[0][0];
        for (int i = tid; i < TT * 9 / 4; i += 256) dst[i] = src[i];
    }
    {
        const float4* src = (const float4*)(o1 + (size_t)b * TT * 2);
        float4* dst = (float4*)&s_l1[0][0];
        for (int i = tid; i < TT * 2 / 4; i += 256) dst[i] = src[i];
    }
    {
        const int4* src = (const int4*)(label + (size_t)b * TT);
        int4* dst = (int4*)s_lab;
        for (int i = tid; i < TT / 4; i += 256) dst[i] = src[i];
    }
    if (tid < 81) s_tr2[tid] = trans2[tid];
    if (tid >= 96 && tid < 100) s_tr1[tid - 96] = trans1[tid - 96];
    for (int i = tid; i < 9 * TT; i += 256) ((unsigned char*)s_bp2)[i] = (unsigned char)(i >> 9);
    for (int i = tid; i < 2 * TT; i += 256) ((unsigned char*)s_bp1)[i] = (unsigned char)(i >> 9);
    __syncthreads();

    // phase 1: lean forward scans (alpha-store only) + score sums
    if (wave == 0) {
        if (lane < 9) {
            const int j = lane;
            float tc0 = s_tr2[0 * 9 + j], tc1 = s_tr2[1 * 9 + j], tc2 = s_tr2[2 * 9 + j];
            float tc3 = s_tr2[3 * 9 + j], tc4 = s_tr2[4 * 9 + j], tc5 = s_tr2[5 * 9 + j];
            float tc6 = s_tr2[6 * 9 + j], tc7 = s_tr2[7 * 9 + j], tc8 = s_tr2[8 * 9 + j];
            float av = s_l2[0][j];
            s_alpha2[0][j] = av;
            float a0 = rl(av, 0), a1 = rl(av, 1), a2 = rl(av, 2);
            float a3 = rl(av, 3), a4 = rl(av, 4), a5 = rl(av, 5);
            float a6 = rl(av, 6), a7 = rl(av, 7), a8 = rl(av, 8);

#define VSTEP2(T, LG) { \
            float v0=a0+tc0, v1=a1+tc1, v2=a2+tc2, v3=a3+tc3, v4=a4+tc4; \
            float v5=a5+tc5, v6=a6+tc6, v7=a7+tc7, v8=a8+tc8; \
            float mm = fmax3(fmax3(v0,v1,v2), fmax3(v3,v4,v5), fmax3(v6,v7,v8)); \
            float nj = mm + (LG); \
            s_alpha2[T][j] = nj; \
            a0=rl(nj,0); a1=rl(nj,1); a2=rl(nj,2); a3=rl(nj,3); a4=rl(nj,4); \
            a5=rl(nj,5); a6=rl(nj,6); a7=rl(nj,7); a8=rl(nj,8); }

            for (int t = 1; t < 8 && t < sl; ++t) {
                float lg = s_l2[t][j];
                VSTEP2(t, lg);
            }
            int t0 = 8;
            for (; t0 + 8 <= sl; t0 += 8) {
                float l0 = s_l2[t0 + 0][j], l1 = s_l2[t0 + 1][j];
                float l2 = s_l2[t0 + 2][j], l3 = s_l2[t0 + 3][j];
                float l4 = s_l2[t0 + 4][j], l5 = s_l2[t0 + 5][j];
                float l6 = s_l2[t0 + 6][j], l7 = s_l2[t0 + 7][j];
                VSTEP2(t0 + 0, l0); VSTEP2(t0 + 1, l1);
                VSTEP2(t0 + 2, l2); VSTEP2(t0 + 3, l3);
                VSTEP2(t0 + 4, l4); VSTEP2(t0 + 5, l5);
                VSTEP2(t0 + 6, l6); VSTEP2(t0 + 7, l7);
            }
            for (int t = t0; t < sl; ++t) {
                float lg = s_l2[t][j];
                VSTEP2(t, lg);
            }
#undef VSTEP2
            if (lane == 0) {
                float mm = fmax3(fmax3(a0, a1, a2), fmax3(a3, a4, a5), fmax3(a6, a7, a8));
                int c0 = (a0 == mm) ? 0 : 15, c1 = (a1 == mm) ? 1 : 15, c2 = (a2 == mm) ? 2 : 15;
                int c3 = (a3 == mm) ? 3 : 15, c4 = (a4 == mm) ? 4 : 15, c5 = (a5 == mm) ? 5 : 15;
                int c6 = (a6 == mm) ? 6 : 15, c7 = (a7 == mm) ? 7 : 15, c8 = (a8 == mm) ? 8 : 15;
                s_last2 = imin3(imin3(c0, c1, c2), imin3(c3, c4, c5), imin3(c6, c7, c8));
            }
        }
    } else if (wave == 1) {
        if (lane < 2) {
            const int j = lane;
            float tc0 = s_tr1[0 * 2 + j], tc1 = s_tr1[1 * 2 + j];
            float av = s_l1[0][j];
            s_alpha1[0][j] = av;
            float a0 = rl(av, 0), a1 = rl(av, 1);

#define VSTEP1(T, LG) { \
            float v0 = a0 + tc0, v1 = a1 + tc1; \
            float nj = fmaxf(v0, v1) + (LG); \
            s_alpha1[T][j] = nj; \
            a0 = rl(nj, 0); a1 = rl(nj, 1); }

            for (int t = 1; t < 8 && t < sl; ++t) {
                float lg = s_l1[t][j];
                VSTEP1(t, lg);
            }
            int t0 = 8;
            for (; t0 + 8 <= sl; t0 += 8) {
                float l0 = s_l1[t0 + 0][j], l1 = s_l1[t0 + 1][j];
                float l2 = s_l1[t0 + 2][j], l3 = s_l1[t0 + 3][j];
                float l4 = s_l1[t0 + 4][j], l5 = s_l1[t0 + 5][j];
                float l6 = s_l1[t0 + 6][j], l7 = s_l1[t0 + 7][j];
                VSTEP1(t0 + 0, l0); VSTEP1(t0 + 1, l1);
                VSTEP1(t0 + 2, l2); VSTEP1(t0 + 3, l3);
                VSTEP1(t0 + 4, l4); VSTEP1(t0 + 5, l5);
                VSTEP1(t0 + 6, l6); VSTEP1(t0 + 7, l7);
            }
            for (int t = t0; t < sl; ++t) {
                float lg = s_l1[t][j];
                VSTEP1(t, lg);
            }
#undef VSTEP1
            if (lane == 0) s_last1 = (a1 > a0) ? 1 : 0;
        }
    } else {
        const int t0i = tid - 128;
        float u1 = 0.f, bs1 = 0.f, u2 = 0.f, bs2 = 0.f;
        for (int t = t0i; t < sl; t += 128) {
            int lb = s_lab[t]; int lb1 = lb > 0 ? 1 : 0;
            u1 += s_l1[t][lb1];
            u2 += s_l2[t][lb];
            if (t >= 1) {
                int lp = s_lab[t - 1]; int lp1 = lp > 0 ? 1 : 0;
                bs1 += s_tr1[lp1 * 2 + lb1];
                bs2 += s_tr2[lp * 9 + lb];
            }
        }
        for (int off = 32; off; off >>= 1) {
            u1 += __shfl_down(u1, off); bs1 += __shfl_down(bs1, off);
            u2 += __shfl_down(u2, off); bs2 += __shfl_down(bs2, off);
        }
        if (lane == 0) {
            s_part[wave - 2][0] = u1; s_part[wave - 2][1] = bs1;
            s_part[wave - 2][2] = u2; s_part[wave - 2][3] = bs2;
        }
    }
    __syncthreads();

    // phase 2a: PARALLEL backpointer reconstruction from stored alphas.
    // Bit-exact vs in-scan computation: same operands, same expressions;
    // fp max is exact, so mm and all comparisons reproduce identically.
    if (tid < 252) {
        const int j = tid % 9;           // 28 threads per column
        const int tq = tid / 9;          // 0..27
        float tc0 = s_tr2[0 * 9 + j], tc1 = s_tr2[1 * 9 + j], tc2 = s_tr2[2 * 9 + j];
        float tc3 = s_tr2[3 * 9 + j], tc4 = s_tr2[4 * 9 + j], tc5 = s_tr2[5 * 9 + j];
        float tc6 = s_tr2[6 * 9 + j], tc7 = s_tr2[7 * 9 + j], tc8 = s_tr2[8 * 9 + j];
        for (int t = 1 + tq; t < sl; t += 28) {
            const float* ap = &s_alpha2[t - 1][0];
            float v0 = ap[0] + tc0, v1 = ap[1] + tc1, v2 = ap[2] + tc2;
            float v3 = ap[3] + tc3, v4 = ap[4] + tc4, v5 = ap[5] + tc5;
            float v6 = ap[6] + tc6, v7 = ap[7] + tc7, v8 = ap[8] + tc8;
            float mm = fmax3(fmax3(v0, v1, v2), fmax3(v3, v4, v5), fmax3(v6, v7, v8));
            int c0 = (v0 == mm) ? 0 : 15, c1 = (v1 == mm) ? 1 : 15, c2 = (v2 == mm) ? 2 : 15;
            int c3 = (v3 == mm) ? 3 : 15, c4 = (v4 == mm) ? 4 : 15, c5 = (v5 == mm) ? 5 : 15;
            int c6 = (v6 == mm) ? 6 : 15, c7 = (v7 == mm) ? 7 : 15, c8 = (v8 == mm) ? 8 : 15;
            int bi = imin3(imin3(c0, c1, c2), imin3(c3, c4, c5), imin3(c6, c7, c8));
            s_bp2[j][t] = (unsigned char)bi;
        }
    }
    {
        const int j1 = tid & 1;
        float t10 = s_tr1[0 * 2 + j1], t11 = s_tr1[1 * 2 + j1];
        for (int t = 1 + (tid >> 1); t < sl; t += 128) {
            float v0 = s_alpha1[t - 1][0] + t10;
            float v1 = s_alpha1[t - 1][1] + t11;
            s_bp1[j1][t] = (unsigned char)((v1 > v0) ? 1 : 0);
        }
    }
    __syncthreads();

    // phase 2b: chunk-parallel backtraces (16 chunks x 32 steps, exact)
    if (tid < 144) {
        int cch = tid / 9, e = tid - cch * 9;
        int pe = (cch < 15) ? (cch + 1) * 32 : 511;
        int tag = e;
        for (int t = pe; t > cch * 32; --t) {
            tag = s_bp2[tag][t];
            s_path2[cch][e][t - 1 - cch * 32] = (unsigned char)tag;
        }
    } else if (tid >= 160 && tid < 192) {
        int k = tid - 160, cch = k >> 1, e = k & 1;
        int pe = (cch < 15) ? (cch + 1) * 32 : 511;
        int tag = e;
        for (int t = pe; t > cch * 32; --t) {
            tag = s_bp1[tag][t];
            s_path1[cch][e][t - 1 - cch * 32] = (unsigned char)tag;
        }
    } else if (tid >= 224 && tid < 228) {
        int k = tid - 224;
        scores[b * 4 + k] = s_part[0][k] + s_part[1][k];
    }
    __syncthreads();

    // phase 3: boundary resolve
    if (tid == 0) {
        int cur = s_last2;
        for (int c = 15; c >= 0; --c) { s_sel2[c] = (unsigned char)cur; cur = s_path2[c][cur][0]; }
    } else if (tid == 1) {
        int cur = s_last1;
        for (int c = 15; c >= 0; --c) { s_sel1[c] = (unsigned char)cur; cur = s_path1[c][cur][0]; }
    }
    __syncthreads();

    // phase 4: assemble tags + accuracy counts
    {
        int c1 = 0, c2 = 0, cc = 0;
        for (int p = tid; p < TT; p += 256) {
            int ch = p >> 5;
            int v2 = (p == 511) ? s_last2 : (int)s_path2[ch][s_sel2[ch]][p & 31];
            int v1 = (p == 511) ? s_last1 : (int)s_path1[ch][s_sel1[ch]][p & 31];
            int comb = (v1 == 0) ? 0 : v2;
            dout[(size_t)b * TT + p] = (float)comb;
            if (p < sl) {
                int lb = s_lab[p]; int lb1 = lb > 0 ? 1 : 0;
                c1 += (v1 == lb1); c2 += (v2 == lb); cc += (comb == lb);
            }
        }
        for (int off = 32; off; off >>= 1) {
            c1 += __shfl_down(c1, off); c2 += __shfl_down(c2, off); cc += __shfl_down(cc, off);
        }
        if (lane == 0) { s_cnt[wave][0] = c1; s_cnt[wave][1] = c2; s_cnt[wave][2] = cc; }
    }
    __syncthreads();
    if (tid == 0) {
        counts[b * 3 + 0] = (float)(s_cnt[0][0] + s_cnt[1][0] + s_cnt[2][0] + s_cnt[3][0]);
        counts[b * 3 + 1] = (float)(s_cnt[0][1] + s_cnt[1][1] + s_cnt[2][1] + s_cnt[3][1]);
        counts[b * 3 + 2] = (float)(s_cnt[0][2] + s_cnt[1][2] + s_cnt[2][2] + s_cnt[3][2]);
    }
}

// ---------------------------------------------------------------------------
// Kernel 3: per-seq fold of 16 chunk matrices (LDS-staged) -> log-norm -> ll.
// Grid 64 x 64 (one wave per seq).
// ---------------------------------------------------------------------------
__global__ __launch_bounds__(64) void finalize_kernel(
    const float* __restrict__ o1, const float* __restrict__ o2,
    const float* __restrict__ M1, const float* __restrict__ M2,
    const float* __restrict__ scores,
    float* __restrict__ ll1, float* __restrict__ ll2)
{
    __shared__ float sM2[16 * 81];
    __shared__ float sM1[16 * 4];
    const int s = blockIdx.x, lane = threadIdx.x;

    for (int i = lane; i < 16 * 81; i += 64) sM2[i] = M2[(size_t)s * 16 * 81 + i];
    for (int i = lane; i < 16 * 4;  i += 64) sM1[i] = M1[(size_t)s * 16 * 4 + i];
    __syncthreads();

    if (lane < 9) {
        const int r = lane;
        float av = o2[(size_t)s * TT * 9 + r];
        float a0 = rl(av, 0), a1 = rl(av, 1), a2 = rl(av, 2);
        float a3 = rl(av, 3), a4 = rl(av, 4), a5 = rl(av, 5);
        float a6 = rl(av, 6), a7 = rl(av, 7), a8 = rl(av, 8);
        for (int c = 0; c < 16; ++c) {
            const float* M = &sM2[c * 81];
            float v0 = a0 + M[0 * 9 + r], v1 = a1 + M[1 * 9 + r], v2 = a2 + M[2 * 9 + r];
            float v3 = a3 + M[3 * 9 + r], v4 = a4 + M[4 * 9 + r], v5 = a5 + M[5 * 9 + r];
            float v6 = a6 + M[6 * 9 + r], v7 = a7 + M[7 * 9 + r], v8 = a8 + M[8 * 9 + r];
            float m = fmax3(fmax3(v0, v1, v2), fmax3(v3, v4, v5), fmax3(v6, v7, v8));
            float su = __expf(v0 - m) + __expf(v1 - m) + __expf(v2 - m)
                     + __expf(v3 - m) + __expf(v4 - m) + __expf(v5 - m)
                     + __expf(v6 - m) + __expf(v7 - m) + __expf(v8 - m);
            float na = m + __logf(su);
            a0 = rl(na, 0); a1 = rl(na, 1); a2 = rl(na, 2);
            a3 = rl(na, 3); a4 = rl(na, 4); a5 = rl(na, 5);
            a6 = rl(na, 6); a7 = rl(na, 7); a8 = rl(na, 8);
        }
        if (lane == 0) {
            float m = fmax3(fmax3(a0, a1, a2), fmax3(a3, a4, a5), fmax3(a6, a7, a8));
            float su = __expf(a0 - m) + __expf(a1 - m) + __expf(a2 - m)
                     + __expf(a3 - m) + __expf(a4 - m) + __expf(a5 - m)
                     + __expf(a6 - m) + __expf(a7 - m) + __expf(a8 - m);
            float ln = m + __logf(su);
            ll2[s] = (scores[s * 4 + 2] + scores[s * 4 + 3]) - ln;
        }
    } else if (lane >= 16 && lane < 18) {
        const int jj = lane - 16;
        float av = o1[(size_t)s * TT * 2 + jj];
        float a0 = rl(av, 16), a1 = rl(av, 17);
        for (int c = 0; c < 16; ++c) {
            const float* M = &sM1[c * 4];
            float v0 = a0 + M[0 * 2 + jj], v1 = a1 + M[1 * 2 + jj];
            float mm = fmaxf(v0, v1);
            float na = mm + __logf(__expf(v0 - mm) + __expf(v1 - mm));
            a0 = rl(na, 16); a1 = rl(na, 17);
        }
        if (jj == 0) {
            float mm = fmaxf(a0, a1);
            float ln = mm + __logf(__expf(a0 - mm) + __expf(a1 - mm));
            ll1[s] = (scores[s * 4 + 0] + scores[s * 4 + 1]) - ln;
        }
    }
}

// ---------------------------------------------------------------------------
// Kernel 4: final scalar reduction (1 block, 64 threads)
// ---------------------------------------------------------------------------
__global__ __launch_bounds__(64) void reduce_kernel(
    const float* __restrict__ ll1, const float* __restrict__ ll2,
    const float* __restrict__ counts, const int* __restrict__ seqlen,
    float* __restrict__ out)
{
    const int t = threadIdx.x;
    float v1 = ll1[t], v2 = ll2[t];
    float a1 = counts[t * 3 + 0], a2 = counts[t * 3 + 1], ac = counts[t * 3 + 2];
    float slf = (float)seqlen[t];
    for (int off = 32; off; off >>= 1) {
        v1 += __shfl_down(v1, off); v2 += __shfl_down(v2, off);
        a1 += __shfl_down(a1, off); a2 += __shfl_down(a2, off);
        ac += __shfl_down(ac, off); slf += __shfl_down(slf, off);
    }
    if (t == 0) {
        float loss1 = -v1 / 64.f;
        float loss2 = -v2 / 64.f;
        out[BB * TT + 0] = (loss1 + 8.f * loss2) / 9.f;
        out[BB * TT + 1] = a1 / slf;
        out[BB * TT + 2] = a2 / slf;
        out[BB * TT + 3] = ac / slf;
    }
}

extern "C" void kernel_launch(void* const* d_in, const int* in_sizes, int n_in,
                              void* d_out, int out_size, void* d_ws, size_t ws_size,
                              hipStream_t stream) {
    (void)in_sizes; (void)n_in; (void)out_size; (void)ws_size;
    const float* x      = (const float*)d_in[0];
    const int*   label  = (const int*)d_in[1];
    const int*   seqlen = (const int*)d_in[2];
    const float* W1     = (const float*)d_in[3];
    const float* b1     = (const float*)d_in[4];
    const float* W2     = (const float*)d_in[5];
    const float* b2     = (const float*)d_in[6];
    const float* trans1 = (const float*)d_in[7];
    const float* trans2 = (const float*)d_in[8];
    float* out = (float*)d_out;
    float* ws  = (float*)d_ws;

    float* o1     = ws;                      // 65536
    float* o2     = o1 + BB * TT * 2;        // 294912
    float* M2     = o2 + BB * TT * 9;        // 64*16*81 = 82944
    float* M1     = M2 + 64 * 16 * 81;       // 4096
    float* scores = M1 + 64 * 16 * 4;        // 256
    float* counts = scores + 64 * 4;         // 192
    float* ll1    = counts + 64 * 3;         // 64
    float* ll2    = ll1 + BB;                // 64

    gemm_kernel<<<256, 256, 0, stream>>>(x, W1, b1, W2, b2, o1, o2);
    crf_kernel<<<1088, 256, 0, stream>>>(o1, o2, label, seqlen, trans1, trans2,
                                         out, M1, M2, scores, counts);
    finalize_kernel<<<64, 64, 0, stream>>>(o1, o2, M1, M2, scores, ll1, ll2);
    reduce_kernel<<<1, 64, 0, stream>>>(ll1, ll2, counts, seqlen, out);
}

// Round 10
// 220.138 us; speedup vs baseline: 1.4792x; 1.0099x over previous
//
#include <hip/hip_runtime.h>

#define TT 512
#define BB 64
#define DD 768
#define NEG (-1e30f)

__device__ __forceinline__ float fmax3(float a, float b, float c) {
    return fmaxf(fmaxf(a, b), c);
}
__device__ __forceinline__ int imin3(int a, int b, int c) {
    return min(min(a, b), c);
}
__device__ __forceinline__ float rl(float x, int i) {
    return __int_as_float(__builtin_amdgcn_readlane(__float_as_int(x), i));
}
__device__ __forceinline__ float dot4(float4 a, float4 b) {
    return a.x * b.x + a.y * b.y + a.z * b.z + a.w * b.w;
}
__device__ __forceinline__ void gl_lds16(const float* g, float* l) {
    __builtin_amdgcn_global_load_lds(
        (const __attribute__((address_space(1))) void*)g,
        (__attribute__((address_space(3))) void*)l, 16, 0, 0);
}

// ---------------------------------------------------------------------------
// Kernel 1: fused skinny GEMM, LDS-staged via global_load_lds.
// 512 blocks x 64 rows; x_tile[2][64*64] (32KB) + wT (33KB) => 2 blocks/CU,
// so one block's barrier drain overlaps the other's compute.
// XOR swizzle: LDS position chunk p of row r holds GLOBAL chunk p^(r&15)
// (staging picks the global address; LDS position is HW-fixed). Reader maps
// chunk q -> position q^(r&15): the 8 row-lanes per column group then hit 8
// distinct bank groups -> conflict-free ds_read_b128.
// ---------------------------------------------------------------------------
__global__ __launch_bounds__(256) void gemm_kernel(
    const float* __restrict__ x,
    const float* __restrict__ W1, const float* __restrict__ b1,
    const float* __restrict__ W2, const float* __restrict__ b2,
    float* __restrict__ o1, float* __restrict__ o2)
{
    __shared__ float wT[11][DD];
    __shared__ float x_tile[2][64 * 64];

    const int tid = threadIdx.x;
    const int wave = tid >> 6, lane = tid & 63;

    for (int i = tid; i < 11 * DD; i += 256) {
        int m = i / DD, d = i - m * DD;
        wT[m][d] = (m < 2) ? W1[d * 2 + m] : W2[d * 9 + (m - 2)];
    }

    const int row0 = blockIdx.x * 64;
    // stage tile kt into buffer bf: 4 chunks/thread, swizzled global pick
#define STAGE_TILE(KT, BF) { \
        _Pragma("unroll") \
        for (int i = 0; i < 4; ++i) { \
            const int e = i * 256 + tid; \
            const int r = e >> 4, q = e & 15; \
            const int qg = q ^ (r & 15); \
            const float* gp = x + ((size_t)(row0 + r) * DD + (KT) * 64 + qg * 4); \
            gl_lds16(gp, &x_tile[BF][e * 4]); \
        } }

    STAGE_TILE(0, 0);
    __syncthreads();

    const int c = lane & 7, g = lane >> 3;
    const int rw = wave * 16;           // wave owns rows rw..rw+15

    float acc[2][11];
#pragma unroll
    for (int j = 0; j < 2; ++j)
#pragma unroll
        for (int m = 0; m < 11; ++m) acc[j][m] = 0.f;

    for (int kt = 0; kt < 12; ++kt) {
        const int cur = kt & 1;
        if (kt + 1 < 12) STAGE_TILE(kt + 1, cur ^ 1);

        float4 xa[2], xb[2];
#pragma unroll
        for (int j = 0; j < 2; ++j) {
            const int r = rw + g + 8 * j;
            const int s = r & 15;
            const int pA = (2 * c) ^ s, pB = (2 * c + 1) ^ s;
            xa[j] = *(const float4*)&x_tile[cur][r * 64 + pA * 4];
            xb[j] = *(const float4*)&x_tile[cur][r * 64 + pB * 4];
        }
#pragma unroll
        for (int m = 0; m < 11; ++m) {
            const float* wp = &wT[m][kt * 64 + c * 8];
            float4 wa = *(const float4*)(wp);
            float4 wb = *(const float4*)(wp + 4);
#pragma unroll
            for (int j = 0; j < 2; ++j)
                acc[j][m] += dot4(xa[j], wa) + dot4(xb[j], wb);
        }
        __syncthreads();
    }

    // reduce over the 8 c-lanes
#pragma unroll
    for (int j = 0; j < 2; ++j)
#pragma unroll
        for (int m = 0; m < 11; ++m) {
            acc[j][m] += __shfl_xor(acc[j][m], 1);
            acc[j][m] += __shfl_xor(acc[j][m], 2);
            acc[j][m] += __shfl_xor(acc[j][m], 4);
        }

    if (c == 0) {
        float bb1[2] = { b1[0], b1[1] };
        float bb2[9];
#pragma unroll
        for (int m = 0; m < 9; ++m) bb2[m] = b2[m];
#pragma unroll
        for (int j = 0; j < 2; ++j) {
            const int row = row0 + rw + g + 8 * j;
            o1[row * 2 + 0] = acc[j][0] + bb1[0];
            o1[row * 2 + 1] = acc[j][1] + bb1[1];
#pragma unroll
            for (int m = 0; m < 9; ++m) o2[row * 9 + m] = acc[j][m + 2] + bb2[m];
        }
    }
#undef STAGE_TILE
}

// ---------------------------------------------------------------------------
// Kernel 2: unified CRF kernel (r9, unchanged), grid = 64 + 1024 blocks.
// ---------------------------------------------------------------------------
__global__ __launch_bounds__(256) void crf_kernel(
    const float* __restrict__ o1, const float* __restrict__ o2,
    const int* __restrict__ label, const int* __restrict__ seqlen,
    const float* __restrict__ trans1, const float* __restrict__ trans2,
    float* __restrict__ dout,
    float* __restrict__ M1, float* __restrict__ M2,
    float* __restrict__ scores, float* __restrict__ counts)
{
    __shared__ float s_l2[TT][9];
    __shared__ float s_l1[TT][2];
    __shared__ float s_alpha2[TT][9];
    __shared__ float s_alpha1[TT][2];
    __shared__ int   s_lab[TT];
    __shared__ float s_tr2[81];
    __shared__ float s_tr1[4];
    __shared__ unsigned char s_bp2[9][TT];
    __shared__ unsigned char s_bp1[2][TT];
    __shared__ unsigned char s_path2[16][9][36];
    __shared__ unsigned char s_path1[16][2][36];
    __shared__ unsigned char s_sel2[16], s_sel1[16];
    __shared__ float s_part[2][4];
    __shared__ int s_last2, s_last1;
    __shared__ int s_cnt[4][3];

    const int tid  = threadIdx.x;
    const int wave = tid >> 6, lane = tid & 63;

    if (blockIdx.x >= 64) {
        // ================= lse chunk-matrix block (32 steps) =================
        const int bc  = blockIdx.x - 64;
        const int b   = bc >> 4, cch = bc & 15;
        const int sl  = seqlen[b];
        const int t0  = cch * 32 + 1;
        const int cap = (cch < 15) ? 32 : 31;
        int n = sl - t0; n = n < 0 ? 0 : (n > cap ? cap : n);

        for (int i = tid; i < cap * 9; i += 256) {
            int t = i / 9, k = i - t * 9;
            s_l2[t][k] = o2[((size_t)b * TT + t0 + t) * 9 + k];
        }
        for (int i = tid; i < cap * 2; i += 256) {
            int t = i >> 1, k = i & 1;
            s_l1[t][k] = o1[((size_t)b * TT + t0 + t) * 2 + k];
        }
        if (tid < 81) s_tr2[tid] = trans2[tid];
        if (tid >= 128 && tid < 132) s_tr1[tid - 128] = trans1[tid - 128];
        __syncthreads();

        if (wave < 2) {
            int L, i_row, jj, base2; bool active;
            if (wave == 0) {
                if (lane < 63) { active = true;  L = 9; i_row = lane / 9; jj = lane - i_row * 9; base2 = i_row * 9; }
                else           { active = false; L = 9; i_row = 0; jj = 0; base2 = 54; }
            } else {
                if (lane < 18)      { active = true;  L = 9; i_row = 7 + lane / 9; jj = lane % 9; base2 = (lane / 9) * 9; }
                else if (lane < 22) { active = true;  L = 2; i_row = (lane - 18) >> 1; jj = (lane - 18) & 1; base2 = 18 + ((lane - 18) & ~1); }
                else                { active = false; L = 2; i_row = 0; jj = 0; base2 = 18; }
            }

            float tcol[9], row[9];
#pragma unroll
            for (int k = 0; k < 9; ++k) {
                tcol[k] = (k < L) ? ((L == 9) ? s_tr2[k * 9 + jj] : s_tr1[k * 2 + jj]) : NEG;
                row[k]  = (k < L && k == i_row) ? 0.f : NEG;
            }
            const float* lp = (L == 9) ? &s_l2[0][jj] : &s_l1[0][jj];
            const int lstride = L;

            for (int tt = 0; tt < n; ++tt) {
                float l = lp[tt * lstride];
                float v[9];
#pragma unroll
                for (int k = 0; k < 9; ++k) v[k] = row[k] + tcol[k];
                float m = fmax3(fmax3(v[0], v[1], v[2]), fmax3(v[3], v[4], v[5]), fmax3(v[6], v[7], v[8]));
                float s = 0.f;
#pragma unroll
                for (int k = 0; k < 9; ++k) s += __expf(v[k] - m);
                float nv = m + __logf(s) + l;
#pragma unroll
                for (int k = 0; k < 9; ++k) {
                    float sv = __shfl(nv, base2 + (k < L ? k : 0));
                    row[k] = (k < L) ? sv : NEG;
                }
            }
            if (active) {
                if (L == 9) M2[((size_t)(b * 16 + cch)) * 81 + i_row * 9 + jj] = row[jj];
                else        M1[((size_t)(b * 16 + cch)) * 4  + i_row * 2 + jj] = row[jj];
            }
        }
        return;
    }

    // ================= per-sequence Viterbi block =================
    const int b  = blockIdx.x;
    const int sl = seqlen[b];

    {
        const float4* src = (const float4*)(o2 + (size_t)b * TT * 9);
        float4* dst = (float4*)&s_l2[0][0];
        for (int i = tid; i < TT * 9 / 4; i += 256) dst[i] = src[i];
    }
    {
        const float4* src = (const float4*)(o1 + (size_t)b * TT * 2);
        float4* dst = (float4*)&s_l1[0][0];
        for (int i = tid; i < TT * 2 / 4; i += 256) dst[i] = src[i];
    }
    {
        const int4* src = (const int4*)(label + (size_t)b * TT);
        int4* dst = (int4*)s_lab;
        for (int i = tid; i < TT / 4; i += 256) dst[i] = src[i];
    }
    if (tid < 81) s_tr2[tid] = trans2[tid];
    if (tid >= 96 && tid < 100) s_tr1[tid - 96] = trans1[tid - 96];
    for (int i = tid; i < 9 * TT; i += 256) ((unsigned char*)s_bp2)[i] = (unsigned char)(i >> 9);
    for (int i = tid; i < 2 * TT; i += 256) ((unsigned char*)s_bp1)[i] = (unsigned char)(i >> 9);
    __syncthreads();

    // phase 1: lean forward scans (alpha-store only) + score sums
    if (wave == 0) {
        if (lane < 9) {
            const int j = lane;
            float tc0 = s_tr2[0 * 9 + j], tc1 = s_tr2[1 * 9 + j], tc2 = s_tr2[2 * 9 + j];
            float tc3 = s_tr2[3 * 9 + j], tc4 = s_tr2[4 * 9 + j], tc5 = s_tr2[5 * 9 + j];
            float tc6 = s_tr2[6 * 9 + j], tc7 = s_tr2[7 * 9 + j], tc8 = s_tr2[8 * 9 + j];
            float av = s_l2[0][j];
            s_alpha2[0][j] = av;
            float a0 = rl(av, 0), a1 = rl(av, 1), a2 = rl(av, 2);
            float a3 = rl(av, 3), a4 = rl(av, 4), a5 = rl(av, 5);
            float a6 = rl(av, 6), a7 = rl(av, 7), a8 = rl(av, 8);

#define VSTEP2(T, LG) { \
            float v0=a0+tc0, v1=a1+tc1, v2=a2+tc2, v3=a3+tc3, v4=a4+tc4; \
            float v5=a5+tc5, v6=a6+tc6, v7=a7+tc7, v8=a8+tc8; \
            float mm = fmax3(fmax3(v0,v1,v2), fmax3(v3,v4,v5), fmax3(v6,v7,v8)); \
            float nj = mm + (LG); \
            s_alpha2[T][j] = nj; \
            a0=rl(nj,0); a1=rl(nj,1); a2=rl(nj,2); a3=rl(nj,3); a4=rl(nj,4); \
            a5=rl(nj,5); a6=rl(nj,6); a7=rl(nj,7); a8=rl(nj,8); }

            for (int t = 1; t < 8 && t < sl; ++t) {
                float lg = s_l2[t][j];
                VSTEP2(t, lg);
            }
            int t0 = 8;
            for (; t0 + 8 <= sl; t0 += 8) {
                float l0 = s_l2[t0 + 0][j], l1 = s_l2[t0 + 1][j];
                float l2 = s_l2[t0 + 2][j], l3 = s_l2[t0 + 3][j];
                float l4 = s_l2[t0 + 4][j], l5 = s_l2[t0 + 5][j];
                float l6 = s_l2[t0 + 6][j], l7 = s_l2[t0 + 7][j];
                VSTEP2(t0 + 0, l0); VSTEP2(t0 + 1, l1);
                VSTEP2(t0 + 2, l2); VSTEP2(t0 + 3, l3);
                VSTEP2(t0 + 4, l4); VSTEP2(t0 + 5, l5);
                VSTEP2(t0 + 6, l6); VSTEP2(t0 + 7, l7);
            }
            for (int t = t0; t < sl; ++t) {
                float lg = s_l2[t][j];
                VSTEP2(t, lg);
            }
#undef VSTEP2
            if (lane == 0) {
                float mm = fmax3(fmax3(a0, a1, a2), fmax3(a3, a4, a5), fmax3(a6, a7, a8));
                int c0 = (a0 == mm) ? 0 : 15, c1 = (a1 == mm) ? 1 : 15, c2 = (a2 == mm) ? 2 : 15;
                int c3 = (a3 == mm) ? 3 : 15, c4 = (a4 == mm) ? 4 : 15, c5 = (a5 == mm) ? 5 : 15;
                int c6 = (a6 == mm) ? 6 : 15, c7 = (a7 == mm) ? 7 : 15, c8 = (a8 == mm) ? 8 : 15;
                s_last2 = imin3(imin3(c0, c1, c2), imin3(c3, c4, c5), imin3(c6, c7, c8));
            }
        }
    } else if (wave == 1) {
        if (lane < 2) {
            const int j = lane;
            float tc0 = s_tr1[0 * 2 + j], tc1 = s_tr1[1 * 2 + j];
            float av = s_l1[0][j];
            s_alpha1[0][j] = av;
            float a0 = rl(av, 0), a1 = rl(av, 1);

#define VSTEP1(T, LG) { \
            float v0 = a0 + tc0, v1 = a1 + tc1; \
            float nj = fmaxf(v0, v1) + (LG); \
            s_alpha1[T][j] = nj; \
            a0 = rl(nj, 0); a1 = rl(nj, 1); }

            for (int t = 1; t < 8 && t < sl; ++t) {
                float lg = s_l1[t][j];
                VSTEP1(t, lg);
            }
            int t0 = 8;
            for (; t0 + 8 <= sl; t0 += 8) {
                float l0 = s_l1[t0 + 0][j], l1 = s_l1[t0 + 1][j];
                float l2 = s_l1[t0 + 2][j], l3 = s_l1[t0 + 3][j];
                float l4 = s_l1[t0 + 4][j], l5 = s_l1[t0 + 5][j];
                float l6 = s_l1[t0 + 6][j], l7 = s_l1[t0 + 7][j];
                VSTEP1(t0 + 0, l0); VSTEP1(t0 + 1, l1);
                VSTEP1(t0 + 2, l2); VSTEP1(t0 + 3, l3);
                VSTEP1(t0 + 4, l4); VSTEP1(t0 + 5, l5);
                VSTEP1(t0 + 6, l6); VSTEP1(t0 + 7, l7);
            }
            for (int t = t0; t < sl; ++t) {
                float lg = s_l1[t][j];
                VSTEP1(t, lg);
            }
#undef VSTEP1
            if (lane == 0) s_last1 = (a1 > a0) ? 1 : 0;
        }
    } else {
        const int t0i = tid - 128;
        float u1 = 0.f, bs1 = 0.f, u2 = 0.f, bs2 = 0.f;
        for (int t = t0i; t < sl; t += 128) {
            int lb = s_lab[t]; int lb1 = lb > 0 ? 1 : 0;
            u1 += s_l1[t][lb1];
            u2 += s_l2[t][lb];
            if (t >= 1) {
                int lp = s_lab[t - 1]; int lp1 = lp > 0 ? 1 : 0;
                bs1 += s_tr1[lp1 * 2 + lb1];
                bs2 += s_tr2[lp * 9 + lb];
            }
        }
        for (int off = 32; off; off >>= 1) {
            u1 += __shfl_down(u1, off); bs1 += __shfl_down(bs1, off);
            u2 += __shfl_down(u2, off); bs2 += __shfl_down(bs2, off);
        }
        if (lane == 0) {
            s_part[wave - 2][0] = u1; s_part[wave - 2][1] = bs1;
            s_part[wave - 2][2] = u2; s_part[wave - 2][3] = bs2;
        }
    }
    __syncthreads();

    // phase 2a: parallel backpointer reconstruction (bit-exact)
    if (tid < 252) {
        const int j = tid % 9;
        const int tq = tid / 9;
        float tc0 = s_tr2[0 * 9 + j], tc1 = s_tr2[1 * 9 + j], tc2 = s_tr2[2 * 9 + j];
        float tc3 = s_tr2[3 * 9 + j], tc4 = s_tr2[4 * 9 + j], tc5 = s_tr2[5 * 9 + j];
        float tc6 = s_tr2[6 * 9 + j], tc7 = s_tr2[7 * 9 + j], tc8 = s_tr2[8 * 9 + j];
        for (int t = 1 + tq; t < sl; t += 28) {
            const float* ap = &s_alpha2[t - 1][0];
            float v0 = ap[0] + tc0, v1 = ap[1] + tc1, v2 = ap[2] + tc2;
            float v3 = ap[3] + tc3, v4 = ap[4] + tc4, v5 = ap[5] + tc5;
            float v6 = ap[6] + tc6, v7 = ap[7] + tc7, v8 = ap[8] + tc8;
            float mm = fmax3(fmax3(v0, v1, v2), fmax3(v3, v4, v5), fmax3(v6, v7, v8));
            int c0 = (v0 == mm) ? 0 : 15, c1 = (v1 == mm) ? 1 : 15, c2 = (v2 == mm) ? 2 : 15;
            int c3 = (v3 == mm) ? 3 : 15, c4 = (v4 == mm) ? 4 : 15, c5 = (v5 == mm) ? 5 : 15;
            int c6 = (v6 == mm) ? 6 : 15, c7 = (v7 == mm) ? 7 : 15, c8 = (v8 == mm) ? 8 : 15;
            int bi = imin3(imin3(c0, c1, c2), imin3(c3, c4, c5), imin3(c6, c7, c8));
            s_bp2[j][t] = (unsigned char)bi;
        }
    }
    {
        const int j1 = tid & 1;
        float t10 = s_tr1[0 * 2 + j1], t11 = s_tr1[1 * 2 + j1];
        for (int t = 1 + (tid >> 1); t < sl; t += 128) {
            float v0 = s_alpha1[t - 1][0] + t10;
            float v1 = s_alpha1[t - 1][1] + t11;
            s_bp1[j1][t] = (unsigned char)((v1 > v0) ? 1 : 0);
        }
    }
    __syncthreads();

    // phase 2b: chunk-parallel backtraces
    if (tid < 144) {
        int cch = tid / 9, e = tid - cch * 9;
        int pe = (cch < 15) ? (cch + 1) * 32 : 511;
        int tag = e;
        for (int t = pe; t > cch * 32; --t) {
            tag = s_bp2[tag][t];
            s_path2[cch][e][t - 1 - cch * 32] = (unsigned char)tag;
        }
    } else if (tid >= 160 && tid < 192) {
        int k = tid - 160, cch = k >> 1, e = k & 1;
        int pe = (cch < 15) ? (cch + 1) * 32 : 511;
        int tag = e;
        for (int t = pe; t > cch * 32; --t) {
            tag = s_bp1[tag][t];
            s_path1[cch][e][t - 1 - cch * 32] = (unsigned char)tag;
        }
    } else if (tid >= 224 && tid < 228) {
        int k = tid - 224;
        scores[b * 4 + k] = s_part[0][k] + s_part[1][k];
    }
    __syncthreads();

    // phase 3: boundary resolve
    if (tid == 0) {
        int cur = s_last2;
        for (int c = 15; c >= 0; --c) { s_sel2[c] = (unsigned char)cur; cur = s_path2[c][cur][0]; }
    } else if (tid == 1) {
        int cur = s_last1;
        for (int c = 15; c >= 0; --c) { s_sel1[c] = (unsigned char)cur; cur = s_path1[c][cur][0]; }
    }
    __syncthreads();

    // phase 4: assemble tags + accuracy counts
    {
        int c1 = 0, c2 = 0, cc = 0;
        for (int p = tid; p < TT; p += 256) {
            int ch = p >> 5;
            int v2 = (p == 511) ? s_last2 : (int)s_path2[ch][s_sel2[ch]][p & 31];
            int v1 = (p == 511) ? s_last1 : (int)s_path1[ch][s_sel1[ch]][p & 31];
            int comb = (v1 == 0) ? 0 : v2;
            dout[(size_t)b * TT + p] = (float)comb;
            if (p < sl) {
                int lb = s_lab[p]; int lb1 = lb > 0 ? 1 : 0;
                c1 += (v1 == lb1); c2 += (v2 == lb); cc += (comb == lb);
            }
        }
        for (int off = 32; off; off >>= 1) {
            c1 += __shfl_down(c1, off); c2 += __shfl_down(c2, off); cc += __shfl_down(cc, off);
        }
        if (lane == 0) { s_cnt[wave][0] = c1; s_cnt[wave][1] = c2; s_cnt[wave][2] = cc; }
    }
    __syncthreads();
    if (tid == 0) {
        counts[b * 3 + 0] = (float)(s_cnt[0][0] + s_cnt[1][0] + s_cnt[2][0] + s_cnt[3][0]);
        counts[b * 3 + 1] = (float)(s_cnt[0][1] + s_cnt[1][1] + s_cnt[2][1] + s_cnt[3][1]);
        counts[b * 3 + 2] = (float)(s_cnt[0][2] + s_cnt[1][2] + s_cnt[2][2] + s_cnt[3][2]);
    }
}

// ---------------------------------------------------------------------------
// Kernel 3: per-seq fold of 16 chunk matrices (LDS-staged) -> ll (r9).
// ---------------------------------------------------------------------------
__global__ __launch_bounds__(64) void finalize_kernel(
    const float* __restrict__ o1, const float* __restrict__ o2,
    const float* __restrict__ M1, const float* __restrict__ M2,
    const float* __restrict__ scores,
    float* __restrict__ ll1, float* __restrict__ ll2)
{
    __shared__ float sM2[16 * 81];
    __shared__ float sM1[16 * 4];
    const int s = blockIdx.x, lane = threadIdx.x;

    for (int i = lane; i < 16 * 81; i += 64) sM2[i] = M2[(size_t)s * 16 * 81 + i];
    for (int i = lane; i < 16 * 4;  i += 64) sM1[i] = M1[(size_t)s * 16 * 4 + i];
    __syncthreads();

    if (lane < 9) {
        const int r = lane;
        float av = o2[(size_t)s * TT * 9 + r];
        float a0 = rl(av, 0), a1 = rl(av, 1), a2 = rl(av, 2);
        float a3 = rl(av, 3), a4 = rl(av, 4), a5 = rl(av, 5);
        float a6 = rl(av, 6), a7 = rl(av, 7), a8 = rl(av, 8);
        for (int c = 0; c < 16; ++c) {
            const float* M = &sM2[c * 81];
            float v0 = a0 + M[0 * 9 + r], v1 = a1 + M[1 * 9 + r], v2 = a2 + M[2 * 9 + r];
            float v3 = a3 + M[3 * 9 + r], v4 = a4 + M[4 * 9 + r], v5 = a5 + M[5 * 9 + r];
            float v6 = a6 + M[6 * 9 + r], v7 = a7 + M[7 * 9 + r], v8 = a8 + M[8 * 9 + r];
            float m = fmax3(fmax3(v0, v1, v2), fmax3(v3, v4, v5), fmax3(v6, v7, v8));
            float su = __expf(v0 - m) + __expf(v1 - m) + __expf(v2 - m)
                     + __expf(v3 - m) + __expf(v4 - m) + __expf(v5 - m)
                     + __expf(v6 - m) + __expf(v7 - m) + __expf(v8 - m);
            float na = m + __logf(su);
            a0 = rl(na, 0); a1 = rl(na, 1); a2 = rl(na, 2);
            a3 = rl(na, 3); a4 = rl(na, 4); a5 = rl(na, 5);
            a6 = rl(na, 6); a7 = rl(na, 7); a8 = rl(na, 8);
        }
        if (lane == 0) {
            float m = fmax3(fmax3(a0, a1, a2), fmax3(a3, a4, a5), fmax3(a6, a7, a8));
            float su = __expf(a0 - m) + __expf(a1 - m) + __expf(a2 - m)
                     + __expf(a3 - m) + __expf(a4 - m) + __expf(a5 - m)
                     + __expf(a6 - m) + __expf(a7 - m) + __expf(a8 - m);
            float ln = m + __logf(su);
            ll2[s] = (scores[s * 4 + 2] + scores[s * 4 + 3]) - ln;
        }
    } else if (lane >= 16 && lane < 18) {
        const int jj = lane - 16;
        float av = o1[(size_t)s * TT * 2 + jj];
        float a0 = rl(av, 16), a1 = rl(av, 17);
        for (int c = 0; c < 16; ++c) {
            const float* M = &sM1[c * 4];
            float v0 = a0 + M[0 * 2 + jj], v1 = a1 + M[1 * 2 + jj];
            float mm = fmaxf(v0, v1);
            float na = mm + __logf(__expf(v0 - mm) + __expf(v1 - mm));
            a0 = rl(na, 16); a1 = rl(na, 17);
        }
        if (jj == 0) {
            float mm = fmaxf(a0, a1);
            float ln = mm + __logf(__expf(a0 - mm) + __expf(a1 - mm));
            ll1[s] = (scores[s * 4 + 0] + scores[s * 4 + 1]) - ln;
        }
    }
}

// ---------------------------------------------------------------------------
// Kernel 4: final scalar reduction (1 block, 64 threads)
// ---------------------------------------------------------------------------
__global__ __launch_bounds__(64) void reduce_kernel(
    const float* __restrict__ ll1, const float* __restrict__ ll2,
    const float* __restrict__ counts, const int* __restrict__ seqlen,
    float* __restrict__ out)
{
    const int t = threadIdx.x;
    float v1 = ll1[t], v2 = ll2[t];
    float a1 = counts[t * 3 + 0], a2 = counts[t * 3 + 1], ac = counts[t * 3 + 2];
    float slf = (float)seqlen[t];
    for (int off = 32; off; off >>= 1) {
        v1 += __shfl_down(v1, off); v2 += __shfl_down(v2, off);
        a1 += __shfl_down(a1, off); a2 += __shfl_down(a2, off);
        ac += __shfl_down(ac, off); slf += __shfl_down(slf, off);
    }
    if (t == 0) {
        float loss1 = -v1 / 64.f;
        float loss2 = -v2 / 64.f;
        out[BB * TT + 0] = (loss1 + 8.f * loss2) / 9.f;
        out[BB * TT + 1] = a1 / slf;
        out[BB * TT + 2] = a2 / slf;
        out[BB * TT + 3] = ac / slf;
    }
}

extern "C" void kernel_launch(void* const* d_in, const int* in_sizes, int n_in,
                              void* d_out, int out_size, void* d_ws, size_t ws_size,
                              hipStream_t stream) {
    (void)in_sizes; (void)n_in; (void)out_size; (void)ws_size;
    const float* x      = (const float*)d_in[0];
    const int*   label  = (const int*)d_in[1];
    const int*   seqlen = (const int*)d_in[2];
    const float* W1     = (const float*)d_in[3];
    const float* b1     = (const float*)d_in[4];
    const float* W2     = (const float*)d_in[5];
    const float* b2     = (const float*)d_in[6];
    const float* trans1 = (const float*)d_in[7];
    const float* trans2 = (const float*)d_in[8];
    float* out = (float*)d_out;
    float* ws  = (float*)d_ws;

    float* o1     = ws;                      // 65536
    float* o2     = o1 + BB * TT * 2;        // 294912
    float* M2     = o2 + BB * TT * 9;        // 64*16*81 = 82944
    float* M1     = M2 + 64 * 16 * 81;       // 4096
    float* scores = M1 + 64 * 16 * 4;        // 256
    float* counts = scores + 64 * 4;         // 192
    float* ll1    = counts + 64 * 3;         // 64
    float* ll2    = ll1 + BB;                // 64

    gemm_kernel<<<512, 256, 0, stream>>>(x, W1, b1, W2, b2, o1, o2);
    crf_kernel<<<1088, 256, 0, stream>>>(o1, o2, label, seqlen, trans1, trans2,
                                         out, M1, M2, scores, counts);
    finalize_kernel<<<64, 64, 0, stream>>>(o1, o2, M1, M2, scores, ll1, ll2);
    reduce_kernel<<<1, 64, 0, stream>>>(ll1, ll2, counts, seqlen, out);
}